// Round 2
// baseline (1014.418 us; speedup 1.0000x reference)
//
#include <hip/hip_runtime.h>
#include <hip/hip_bf16.h>

#define N_SUP 16384
#define M_Q   4096
#define TV    27
#define CIN   41
#define CH1   864
#define CH2   128
#define CAP   1024

// lexicographic (dist, index) compare -- matches jax.lax.top_k tie-break (lowest index wins)
__device__ __forceinline__ bool lt3(float da, int ia, float db, int ib){
  return (da < db) || ((da == db) && (ia < ib));
}

__device__ __forceinline__ void ins3(float d, int i, int s,
    float& d0, int& i0, int& s0,
    float& d1, int& i1, int& s1,
    float& d2, int& i2, int& s2){
  if (lt3(d, i, d2, i2)) {
    if (lt3(d, i, d1, i1)) {
      d2 = d1; i2 = i1; s2 = s1;
      if (lt3(d, i, d0, i0)) { d1 = d0; i1 = i0; s1 = s0; d0 = d; i0 = i; s0 = s; }
      else                   { d1 = d;  i1 = i;  s1 = s; }
    } else { d2 = d; i2 = i; s2 = s; }
  }
}

// grid offset value for axis-index 0/1/2 : linspace(-R+R/NV, R-R/NV, 3) = {-1.3333334, 0, +1.3333334}
__device__ __forceinline__ float gsel(int i){
  const float GOFF = (float)(-2.0 + 2.0 / 3.0);   // -1.3333334f (matches f32 linspace endpoint)
  return (i == 0) ? GOFF : ((i == 2) ? -GOFF : 0.0f);
}

// ---------------- Kernel A: candidates + 3NN + interp + grouped conv1 ----------------
__global__ __launch_bounds__(256) void kA(const float* __restrict__ sup_xyz,
                                          const float* __restrict__ sup_feat,
                                          const float* __restrict__ new_xyz,
                                          const float* __restrict__ w1,
                                          float* __restrict__ y1)
{
  __shared__ float cxl[CAP], cyl[CAP], czl[CAP];
  __shared__ unsigned short cil[CAP];
  __shared__ int s_cnt;
  __shared__ float s_w[TV][3];
  __shared__ int   s_gi[TV][3];
  __shared__ short s_sl[TV][3];
  __shared__ float s_feats[TV][CIN];

  const int m   = blockIdx.x;
  const int tid = threadIdx.x;
  if (tid == 0) s_cnt = 0;
  __syncthreads();

  const float qx = new_xyz[m*3+0];
  const float qy = new_xyz[m*3+1];
  const float qz = new_xyz[m*3+2];

  // ---- phase 1: cube filter (|s - q|_inf <= MULT*R = 4.0) ----
  for (int i = tid; i < N_SUP; i += 256) {
    float sx = sup_xyz[i*3+0];
    float sy = sup_xyz[i*3+1];
    float sz = sup_xyz[i*3+2];
    if (fabsf(sx - qx) <= 4.0f && fabsf(sy - qy) <= 4.0f && fabsf(sz - qz) <= 4.0f) {
      int p = atomicAdd(&s_cnt, 1);
      if (p < CAP) { cxl[p] = sx; cyl[p] = sy; czl[p] = sz; cil[p] = (unsigned short)i; }
    }
  }
  __syncthreads();
  const int cnt = (s_cnt < CAP) ? s_cnt : CAP;

  // ---- phase 2: per-voxel top-3 (one wave per voxel, round-robin) ----
  const int wv = tid >> 6, lane = tid & 63;
  for (int v = wv; v < TV; v += 4) {
    const int ix = v / 9, iy = (v / 3) % 3, iz = v % 3;
    const float gx = qx + gsel(ix);
    const float gy = qy + gsel(iy);
    const float gz = qz + gsel(iz);

    float d0 = 1e30f, d1 = 1e30f, d2 = 1e30f;
    int   i0 = 0x7fffffff, i1 = 0x7fffffff, i2 = 0x7fffffff;
    int   s0 = 0, s1 = 0, s2 = 0;

    for (int c = lane; c < cnt; c += 64) {
      float dx = __fsub_rn(gx, cxl[c]);
      float dy = __fsub_rn(gy, cyl[c]);
      float dz = __fsub_rn(gz, czl[c]);
      // forbid FMA contraction: must match numpy f32 (mul, mul, add, mul, add)
      float dd = __fadd_rn(__fadd_rn(__fmul_rn(dx,dx), __fmul_rn(dy,dy)), __fmul_rn(dz,dz));
      int gi = (int)cil[c];
      ins3(dd, gi, c, d0,i0,s0, d1,i1,s1, d2,i2,s2);
    }
    // butterfly merge across the 64 lanes
    for (int off = 32; off > 0; off >>= 1) {
      float od0 = __shfl_xor(d0, off, 64);
      float od1 = __shfl_xor(d1, off, 64);
      float od2 = __shfl_xor(d2, off, 64);
      int   oi0 = __shfl_xor(i0, off, 64);
      int   oi1 = __shfl_xor(i1, off, 64);
      int   oi2 = __shfl_xor(i2, off, 64);
      int   os0 = __shfl_xor(s0, off, 64);
      int   os1 = __shfl_xor(s1, off, 64);
      int   os2 = __shfl_xor(s2, off, 64);
      ins3(od0, oi0, os0, d0,i0,s0, d1,i1,s1, d2,i2,s2);
      ins3(od1, oi1, os1, d0,i0,s0, d1,i1,s1, d2,i2,s2);
      ins3(od2, oi2, os2, d0,i0,s0, d1,i1,s1, d2,i2,s2);
    }
    if (lane == 0) {
      float dd0 = (d0 >= 1e29f) ? 1e10f : d0;
      float dd1 = (d1 >= 1e29f) ? 1e10f : d1;
      float dd2 = (d2 >= 1e29f) ? 1e10f : d2;
      float r0 = 1.0f / (dd0 + 1e-8f);
      float r1 = 1.0f / (dd1 + 1e-8f);
      float r2 = 1.0f / (dd2 + 1e-8f);
      float den = fmaxf(r0 + r1 + r2, 1e-8f);
      s_w[v][0] = r0 / den; s_w[v][1] = r1 / den; s_w[v][2] = r2 / den;
      s_gi[v][0] = (i0 < N_SUP) ? i0 : 0;
      s_gi[v][1] = (i1 < N_SUP) ? i1 : 0;
      s_gi[v][2] = (i2 < N_SUP) ? i2 : 0;
      s_sl[v][0] = (short)s0; s_sl[v][1] = (short)s1; s_sl[v][2] = (short)s2;
    }
  }
  __syncthreads();

  // ---- phase 3a: interpolated features (27 voxels x 32 ch) ----
  for (int t = tid; t < TV*32; t += 256) {
    const int v = t >> 5, ch = t & 31;
    float acc = 0.0f;
    if (cnt > 0) {
      acc = s_w[v][0] * sup_feat[s_gi[v][0]*32 + ch]
          + s_w[v][1] * sup_feat[s_gi[v][1]*32 + ch]
          + s_w[v][2] * sup_feat[s_gi[v][2]*32 + ch];
    }
    s_feats[v][ch] = acc;
  }
  // ---- phase 3b: local xyz (27 voxels x 3 nbr x 3 axis) ----
  for (int t = tid; t < TV*9; t += 256) {
    const int v = t / 9, j = t % 9, k = j / 3, ax = j % 3;
    float val = 0.0f;
    if (cnt > 0) {
      int sl = (int)s_sl[v][k];
      float sv = (ax == 0) ? cxl[sl] : ((ax == 1) ? cyl[sl] : czl[sl]);
      int axidx = (ax == 0) ? (v / 9) : ((ax == 1) ? ((v / 3) % 3) : (v % 3));
      float qq  = (ax == 0) ? qx : ((ax == 1) ? qy : qz);
      val = (qq + gsel(axidx)) - sv;
    }
    s_feats[v][32 + j] = val;
  }
  __syncthreads();

  // ---- phase 4: grouped conv1 (41 -> 32 per voxel) ----
  for (int t = tid; t < CH1; t += 256) {
    const int v = t >> 5;
    const float* wrow = w1 + (size_t)t * CIN;   // w1[v][o][k], t = v*32+o
    float acc = 0.0f;
    #pragma unroll
    for (int k = 0; k < CIN; k++) acc += s_feats[v][k] * wrow[k];
    y1[(size_t)m * CH1 + t] = acc;
  }
}

// ---------------- Kernel B: BN1 stats (sum, sumsq per channel over M) ----------------
__global__ void kB(const float* __restrict__ y1, float* __restrict__ stats1)
{
  const int c  = threadIdx.x;        // 864 threads
  const int m0 = blockIdx.x * 256;   // 16 blocks
  float s = 0.0f, ss = 0.0f;
  for (int r = 0; r < 256; r++) {
    float v = y1[(size_t)(m0 + r) * CH1 + c];
    s += v; ss += v * v;
  }
  atomicAdd(&stats1[c],       s);
  atomicAdd(&stats1[CH1 + c], ss);
}

// ---------------- Kernel T: transpose w2 (128x864 f32) -> w2T (864x128 f32) ----------------
__global__ void kT(const float* __restrict__ w2, float* __restrict__ w2T)
{
  int t = blockIdx.x * 256 + threadIdx.x;
  if (t < CH1 * CH2) {
    int k = t / CH2, c = t % CH2;
    w2T[t] = w2[(size_t)c * CH1 + k];
  }
}

// ---------------- Kernel C: BN1 apply + ReLU + GEMM (4096x864 @ 864x128) + BN2 partial stats ----------------
__global__ __launch_bounds__(256) void kC(const float* __restrict__ y1,
                                          const float* __restrict__ stats1,
                                          const float* __restrict__ g1,
                                          const float* __restrict__ b1,
                                          const float* __restrict__ w2T,
                                          float* __restrict__ z,
                                          float* __restrict__ stats2)
{
  __shared__ float yn[16][CH1];
  __shared__ float scs[CH1], shs[CH1];
  const int tid = threadIdx.x;
  const int m0  = blockIdx.x * 16;

  for (int c = tid; c < CH1; c += 256) {
    float s  = stats1[c], ssq = stats1[CH1 + c];
    float mu  = s  * (1.0f / M_Q);
    float var = ssq * (1.0f / M_Q) - mu * mu;
    float r   = 1.0f / sqrtf(var + 1e-5f);
    float gg = g1[c], bb = b1[c];
    scs[c] = r * gg;
    shs[c] = bb - mu * r * gg;
  }
  __syncthreads();

  for (int t = tid; t < 16 * CH1; t += 256) {
    int rr = t / CH1, c = t % CH1;
    float v = y1[(size_t)(m0 + rr) * CH1 + c];
    yn[rr][c] = fmaxf(v * scs[c] + shs[c], 0.0f);
  }
  __syncthreads();

  const int c = tid & 127, rg = tid >> 7;   // rg in {0,1}: rows rg*8 .. rg*8+7
  float acc[8];
  #pragma unroll
  for (int r = 0; r < 8; r++) acc[r] = 0.0f;

  for (int k = 0; k < CH1; k++) {
    float wv = w2T[(size_t)k * CH2 + c];
    #pragma unroll
    for (int r = 0; r < 8; r++) acc[r] += yn[rg*8 + r][k] * wv;
  }

  float s = 0.0f, ss = 0.0f;
  #pragma unroll
  for (int r = 0; r < 8; r++) {
    z[(size_t)(m0 + rg*8 + r) * CH2 + c] = acc[r];
    s += acc[r]; ss += acc[r] * acc[r];
  }
  atomicAdd(&stats2[c],       s);
  atomicAdd(&stats2[CH2 + c], ss);
}

// ---------------- Kernel D: BN2 apply + ReLU -> f32 out ----------------
__global__ void kD(const float* __restrict__ z,
                   const float* __restrict__ stats2,
                   const float* __restrict__ g2,
                   const float* __restrict__ b2,
                   float* __restrict__ out)
{
  int t = blockIdx.x * 256 + threadIdx.x;
  if (t >= M_Q * CH2) return;
  int c = t & 127;
  float s  = stats2[c], ssq = stats2[CH2 + c];
  float mu  = s  * (1.0f / M_Q);
  float var = ssq * (1.0f / M_Q) - mu * mu;
  float r   = 1.0f / sqrtf(var + 1e-5f);
  float val = fmaxf((z[t] - mu) * r * g2[c] + b2[c], 0.0f);
  out[t] = val;
}

extern "C" void kernel_launch(void* const* d_in, const int* in_sizes, int n_in,
                              void* d_out, int out_size, void* d_ws, size_t ws_size,
                              hipStream_t stream)
{
  const float* sup_xyz  = (const float*)d_in[0];
  const float* sup_feat = (const float*)d_in[1];
  const float* new_xyz  = (const float*)d_in[2];
  const float* w1       = (const float*)d_in[3];
  const float* g1       = (const float*)d_in[4];
  const float* b1       = (const float*)d_in[5];
  const float* w2       = (const float*)d_in[6];
  const float* g2       = (const float*)d_in[7];
  const float* b2       = (const float*)d_in[8];
  float* out = (float*)d_out;

  char* ws = (char*)d_ws;
  float* y1     = (float*)(ws);                                   // 4096*864 f32 = 14,155,776 B
  float* z      = (float*)(ws + 14155776);                        // 4096*128 f32 =  2,097,152 B
  float* w2T    = (float*)(ws + 14155776 + 2097152);              //  864*128 f32 =    442,368 B
  float* stats  = (float*)(ws + 14155776 + 2097152 + 442368);     // 1728 + 256 f32
  float* stats1 = stats;
  float* stats2 = stats + 2 * CH1;

  hipMemsetAsync(stats, 0, (2 * CH1 + 2 * CH2) * sizeof(float), stream);

  hipLaunchKernelGGL(kA, dim3(M_Q), dim3(256), 0, stream, sup_xyz, sup_feat, new_xyz, w1, y1);
  hipLaunchKernelGGL(kB, dim3(16), dim3(CH1), 0, stream, y1, stats1);
  hipLaunchKernelGGL(kT, dim3((CH1*CH2 + 255) / 256), dim3(256), 0, stream, w2, w2T);
  hipLaunchKernelGGL(kC, dim3(M_Q / 16), dim3(256), 0, stream, y1, stats1, g1, b1, w2T, z, stats2);
  hipLaunchKernelGGL(kD, dim3((M_Q*CH2 + 255) / 256), dim3(256), 0, stream, z, stats2, g2, b2, out);
}

// Round 3
// 1006.884 us; speedup vs baseline: 1.0075x; 1.0075x over previous
//
#include <hip/hip_runtime.h>
#include <hip/hip_bf16.h>

#define N_SUP 16384
#define M_Q   4096
#define TV    27
#define CIN   41
#define CH1   864
#define CH2   128
#define CAP   1024

// lexicographic (dist, index) compare -- matches jax.lax.top_k tie-break (lowest index wins)
__device__ __forceinline__ bool lt3(float da, int ia, float db, int ib){
  return (da < db) || ((da == db) && (ia < ib));
}

__device__ __forceinline__ void ins3(float d, int i, int s,
    float& d0, int& i0, int& s0,
    float& d1, int& i1, int& s1,
    float& d2, int& i2, int& s2){
  if (lt3(d, i, d2, i2)) {
    if (lt3(d, i, d1, i1)) {
      d2 = d1; i2 = i1; s2 = s1;
      if (lt3(d, i, d0, i0)) { d1 = d0; i1 = i0; s1 = s0; d0 = d; i0 = i; s0 = s; }
      else                   { d1 = d;  i1 = i;  s1 = s; }
    } else { d2 = d; i2 = i; s2 = s; }
  }
}

// grid offset value for axis-index 0/1/2 : linspace(-R+R/NV, R-R/NV, 3) = {-1.3333334, 0, +1.3333334}
__device__ __forceinline__ float gsel(int i){
  const float GOFF = (float)(-2.0 + 2.0 / 3.0);   // -1.3333334f (matches f32 linspace endpoint)
  return (i == 0) ? GOFF : ((i == 2) ? -GOFF : 0.0f);
}

// ---------------- Kernel W: transpose w1 [864][41] -> w1T [41][864] ----------------
__global__ void kW(const float* __restrict__ w1, float* __restrict__ w1T)
{
  int idx = blockIdx.x * 256 + threadIdx.x;      // output-major: coalesced writes
  if (idx < CIN * CH1) {
    int k = idx / CH1, t = idx % CH1;
    w1T[idx] = w1[(size_t)t * CIN + k];
  }
}

// ---------------- Kernel A: candidates + 3NN + interp + grouped conv1 ----------------
__global__ __launch_bounds__(256) void kA(const float* __restrict__ sup_xyz,
                                          const float* __restrict__ sup_feat,
                                          const float* __restrict__ new_xyz,
                                          const float* __restrict__ w1T,
                                          float* __restrict__ y1)
{
  __shared__ float cxl[CAP], cyl[CAP], czl[CAP];
  __shared__ unsigned short cil[CAP];
  __shared__ int s_cnt;
  __shared__ float s_w[TV][3];
  __shared__ int   s_gi[TV][3];
  __shared__ short s_sl[TV][3];
  __shared__ float s_feats[TV][CIN];

  const int m   = blockIdx.x;
  const int tid = threadIdx.x;
  if (tid == 0) s_cnt = 0;
  __syncthreads();

  const float qx = new_xyz[m*3+0];
  const float qy = new_xyz[m*3+1];
  const float qz = new_xyz[m*3+2];

  // ---- phase 1: cube filter (|s - q|_inf <= MULT*R = 4.0) ----
  for (int i = tid; i < N_SUP; i += 256) {
    float sx = sup_xyz[i*3+0];
    float sy = sup_xyz[i*3+1];
    float sz = sup_xyz[i*3+2];
    if (fabsf(sx - qx) <= 4.0f && fabsf(sy - qy) <= 4.0f && fabsf(sz - qz) <= 4.0f) {
      int p = atomicAdd(&s_cnt, 1);
      if (p < CAP) { cxl[p] = sx; cyl[p] = sy; czl[p] = sz; cil[p] = (unsigned short)i; }
    }
  }
  __syncthreads();
  const int cnt = (s_cnt < CAP) ? s_cnt : CAP;

  // ---- phase 2: per-voxel top-3 (one wave per voxel, round-robin) ----
  const int wv = tid >> 6, lane = tid & 63;
  for (int v = wv; v < TV; v += 4) {
    const int ix = v / 9, iy = (v / 3) % 3, iz = v % 3;
    const float gx = qx + gsel(ix);
    const float gy = qy + gsel(iy);
    const float gz = qz + gsel(iz);

    float d0 = 1e30f, d1 = 1e30f, d2 = 1e30f;
    int   i0 = 0x7fffffff, i1 = 0x7fffffff, i2 = 0x7fffffff;
    int   s0 = 0, s1 = 0, s2 = 0;

    for (int c = lane; c < cnt; c += 64) {
      float dx = __fsub_rn(gx, cxl[c]);
      float dy = __fsub_rn(gy, cyl[c]);
      float dz = __fsub_rn(gz, czl[c]);
      // forbid FMA contraction: must match numpy f32 (mul, mul, add, mul, add)
      float dd = __fadd_rn(__fadd_rn(__fmul_rn(dx,dx), __fmul_rn(dy,dy)), __fmul_rn(dz,dz));
      int gi = (int)cil[c];
      ins3(dd, gi, c, d0,i0,s0, d1,i1,s1, d2,i2,s2);
    }
    // butterfly merge across the 64 lanes
    for (int off = 32; off > 0; off >>= 1) {
      float od0 = __shfl_xor(d0, off, 64);
      float od1 = __shfl_xor(d1, off, 64);
      float od2 = __shfl_xor(d2, off, 64);
      int   oi0 = __shfl_xor(i0, off, 64);
      int   oi1 = __shfl_xor(i1, off, 64);
      int   oi2 = __shfl_xor(i2, off, 64);
      int   os0 = __shfl_xor(s0, off, 64);
      int   os1 = __shfl_xor(s1, off, 64);
      int   os2 = __shfl_xor(s2, off, 64);
      ins3(od0, oi0, os0, d0,i0,s0, d1,i1,s1, d2,i2,s2);
      ins3(od1, oi1, os1, d0,i0,s0, d1,i1,s1, d2,i2,s2);
      ins3(od2, oi2, os2, d0,i0,s0, d1,i1,s1, d2,i2,s2);
    }
    if (lane == 0) {
      float dd0 = (d0 >= 1e29f) ? 1e10f : d0;
      float dd1 = (d1 >= 1e29f) ? 1e10f : d1;
      float dd2 = (d2 >= 1e29f) ? 1e10f : d2;
      float r0 = 1.0f / (dd0 + 1e-8f);
      float r1 = 1.0f / (dd1 + 1e-8f);
      float r2 = 1.0f / (dd2 + 1e-8f);
      float den = fmaxf(r0 + r1 + r2, 1e-8f);
      s_w[v][0] = r0 / den; s_w[v][1] = r1 / den; s_w[v][2] = r2 / den;
      s_gi[v][0] = (i0 < N_SUP) ? i0 : 0;
      s_gi[v][1] = (i1 < N_SUP) ? i1 : 0;
      s_gi[v][2] = (i2 < N_SUP) ? i2 : 0;
      s_sl[v][0] = (short)s0; s_sl[v][1] = (short)s1; s_sl[v][2] = (short)s2;
    }
  }
  __syncthreads();

  // ---- phase 3a: interpolated features (27 voxels x 32 ch) ----
  for (int t = tid; t < TV*32; t += 256) {
    const int v = t >> 5, ch = t & 31;
    float acc = 0.0f;
    if (cnt > 0) {
      acc = s_w[v][0] * sup_feat[s_gi[v][0]*32 + ch]
          + s_w[v][1] * sup_feat[s_gi[v][1]*32 + ch]
          + s_w[v][2] * sup_feat[s_gi[v][2]*32 + ch];
    }
    s_feats[v][ch] = acc;
  }
  // ---- phase 3b: local xyz (27 voxels x 3 nbr x 3 axis) ----
  for (int t = tid; t < TV*9; t += 256) {
    const int v = t / 9, j = t % 9, k = j / 3, ax = j % 3;
    float val = 0.0f;
    if (cnt > 0) {
      int sl = (int)s_sl[v][k];
      float sv = (ax == 0) ? cxl[sl] : ((ax == 1) ? cyl[sl] : czl[sl]);
      int axidx = (ax == 0) ? (v / 9) : ((ax == 1) ? ((v / 3) % 3) : (v % 3));
      float qq  = (ax == 0) ? qx : ((ax == 1) ? qy : qz);
      val = (qq + gsel(axidx)) - sv;
    }
    s_feats[v][32 + j] = val;
  }
  __syncthreads();

  // ---- phase 4: grouped conv1 (41 -> 32 per voxel), w1T read coalesced ----
  for (int t = tid; t < CH1; t += 256) {
    const int v = t >> 5;
    float acc = 0.0f;
    #pragma unroll
    for (int k = 0; k < CIN; k++) acc += s_feats[v][k] * w1T[k * CH1 + t];
    y1[(size_t)m * CH1 + t] = acc;
  }
}

// ---------------- Kernel B: BN1 stats (sum, sumsq per channel over M) ----------------
__global__ void kB(const float* __restrict__ y1, float* __restrict__ stats1)
{
  const int c  = threadIdx.x;        // 864 threads
  const int m0 = blockIdx.x * 256;   // 16 blocks
  float s = 0.0f, ss = 0.0f;
  for (int r = 0; r < 256; r++) {
    float v = y1[(size_t)(m0 + r) * CH1 + c];
    s += v; ss += v * v;
  }
  atomicAdd(&stats1[c],       s);
  atomicAdd(&stats1[CH1 + c], ss);
}

// ---------------- Kernel T: transpose w2 (128x864 f32) -> w2T (864x128 f32) ----------------
__global__ void kT(const float* __restrict__ w2, float* __restrict__ w2T)
{
  int t = blockIdx.x * 256 + threadIdx.x;
  if (t < CH1 * CH2) {
    int k = t / CH2, c = t % CH2;
    w2T[t] = w2[(size_t)c * CH1 + k];
  }
}

// ---------------- Kernel C: BN1 apply + ReLU + GEMM (4096x864 @ 864x128) + BN2 partial stats ----------------
__global__ __launch_bounds__(256) void kC(const float* __restrict__ y1,
                                          const float* __restrict__ stats1,
                                          const float* __restrict__ g1,
                                          const float* __restrict__ b1,
                                          const float* __restrict__ w2T,
                                          float* __restrict__ z,
                                          float* __restrict__ stats2)
{
  __shared__ float yn[16][CH1];
  __shared__ float scs[CH1], shs[CH1];
  const int tid = threadIdx.x;
  const int m0  = blockIdx.x * 16;

  for (int c = tid; c < CH1; c += 256) {
    float s  = stats1[c], ssq = stats1[CH1 + c];
    float mu  = s  * (1.0f / M_Q);
    float var = ssq * (1.0f / M_Q) - mu * mu;
    float r   = 1.0f / sqrtf(var + 1e-5f);
    float gg = g1[c], bb = b1[c];
    scs[c] = r * gg;
    shs[c] = bb - mu * r * gg;
  }
  __syncthreads();

  for (int t = tid; t < 16 * CH1; t += 256) {
    int rr = t / CH1, c = t % CH1;
    float v = y1[(size_t)(m0 + rr) * CH1 + c];
    yn[rr][c] = fmaxf(v * scs[c] + shs[c], 0.0f);
  }
  __syncthreads();

  const int c = tid & 127, rg = tid >> 7;   // rg in {0,1}: rows rg*8 .. rg*8+7
  float acc[8];
  #pragma unroll
  for (int r = 0; r < 8; r++) acc[r] = 0.0f;

  for (int k = 0; k < CH1; k++) {
    float wv = w2T[(size_t)k * CH2 + c];
    #pragma unroll
    for (int r = 0; r < 8; r++) acc[r] += yn[rg*8 + r][k] * wv;
  }

  float s = 0.0f, ss = 0.0f;
  #pragma unroll
  for (int r = 0; r < 8; r++) {
    z[(size_t)(m0 + rg*8 + r) * CH2 + c] = acc[r];
    s += acc[r]; ss += acc[r] * acc[r];
  }
  atomicAdd(&stats2[c],       s);
  atomicAdd(&stats2[CH2 + c], ss);
}

// ---------------- Kernel D: BN2 apply + ReLU -> f32 out ----------------
__global__ void kD(const float* __restrict__ z,
                   const float* __restrict__ stats2,
                   const float* __restrict__ g2,
                   const float* __restrict__ b2,
                   float* __restrict__ out)
{
  int t = blockIdx.x * 256 + threadIdx.x;
  if (t >= M_Q * CH2) return;
  int c = t & 127;
  float s  = stats2[c], ssq = stats2[CH2 + c];
  float mu  = s  * (1.0f / M_Q);
  float var = ssq * (1.0f / M_Q) - mu * mu;
  float r   = 1.0f / sqrtf(var + 1e-5f);
  float val = fmaxf((z[t] - mu) * r * g2[c] + b2[c], 0.0f);
  out[t] = val;
}

extern "C" void kernel_launch(void* const* d_in, const int* in_sizes, int n_in,
                              void* d_out, int out_size, void* d_ws, size_t ws_size,
                              hipStream_t stream)
{
  const float* sup_xyz  = (const float*)d_in[0];
  const float* sup_feat = (const float*)d_in[1];
  const float* new_xyz  = (const float*)d_in[2];
  const float* w1       = (const float*)d_in[3];
  const float* g1       = (const float*)d_in[4];
  const float* b1       = (const float*)d_in[5];
  const float* w2       = (const float*)d_in[6];
  const float* g2       = (const float*)d_in[7];
  const float* b2       = (const float*)d_in[8];
  float* out = (float*)d_out;

  char* ws = (char*)d_ws;
  float* y1     = (float*)(ws);                                   // 4096*864 f32 = 14,155,776 B
  float* z      = (float*)(ws + 14155776);                        // 4096*128 f32 =  2,097,152 B
  float* w2T    = (float*)(ws + 14155776 + 2097152);              //  864*128 f32 =    442,368 B
  float* stats  = (float*)(ws + 14155776 + 2097152 + 442368);     // 1728 + 256 f32
  float* stats1 = stats;
  float* stats2 = stats + 2 * CH1;
  // w1T (41*864 f32 = 141,696 B) aliases the z region: z is written only by kC,
  // which runs after kA (the only reader of w1T) has completed. Deterministic
  // across graph replays because kW rewrites it every launch.
  float* w1T    = z;

  hipMemsetAsync(stats, 0, (2 * CH1 + 2 * CH2) * sizeof(float), stream);

  hipLaunchKernelGGL(kW, dim3((CIN*CH1 + 255) / 256), dim3(256), 0, stream, w1, w1T);
  hipLaunchKernelGGL(kA, dim3(M_Q), dim3(256), 0, stream, sup_xyz, sup_feat, new_xyz, w1T, y1);
  hipLaunchKernelGGL(kB, dim3(16), dim3(CH1), 0, stream, y1, stats1);
  hipLaunchKernelGGL(kT, dim3((CH1*CH2 + 255) / 256), dim3(256), 0, stream, w2, w2T);
  hipLaunchKernelGGL(kC, dim3(M_Q / 16), dim3(256), 0, stream, y1, stats1, g1, b1, w2T, z, stats2);
  hipLaunchKernelGGL(kD, dim3((M_Q*CH2 + 255) / 256), dim3(256), 0, stream, z, stats2, g2, b2, out);
}

// Round 4
// 982.678 us; speedup vs baseline: 1.0323x; 1.0246x over previous
//
#include <hip/hip_runtime.h>
#include <hip/hip_bf16.h>

#define N_SUP 16384
#define M_Q   4096
#define TV    27
#define CIN   41
#define CH1   864
#define CH2   128
#define CAP   1024
#define NB    12          // bins per xy axis (width 50/12 = 4.17 >= 4)

// lexicographic (dist, index) compare -- matches jax.lax.top_k tie-break (lowest index wins)
__device__ __forceinline__ bool lt3(float da, int ia, float db, int ib){
  return (da < db) || ((da == db) && (ia < ib));
}

__device__ __forceinline__ void ins3(float d, int i, int s,
    float& d0, int& i0, int& s0,
    float& d1, int& i1, int& s1,
    float& d2, int& i2, int& s2){
  if (lt3(d, i, d2, i2)) {
    if (lt3(d, i, d1, i1)) {
      d2 = d1; i2 = i1; s2 = s1;
      if (lt3(d, i, d0, i0)) { d1 = d0; i1 = i0; s1 = s0; d0 = d; i0 = i; s0 = s; }
      else                   { d1 = d;  i1 = i;  s1 = s; }
    } else { d2 = d; i2 = i; s2 = s; }
  }
}

// grid offset value for axis-index 0/1/2 : linspace(-R+R/NV, R-R/NV, 3) = {-1.3333334, 0, +1.3333334}
__device__ __forceinline__ float gsel(int i){
  const float GOFF = (float)(-2.0 + 2.0 / 3.0);   // -1.3333334f (matches f32 linspace endpoint)
  return (i == 0) ? GOFF : ((i == 2) ? -GOFF : 0.0f);
}

// monotone bin map, identical for points and queries (monotonicity is all correctness needs)
__device__ __forceinline__ int binOf(float x){
  int b = (int)(x * (float)(NB / 50.0));
  return (b < 0) ? 0 : ((b > NB - 1) ? NB - 1 : b);
}

// ---------------- Kernel W: transpose w1 [864][41] -> w1T [41][864] ----------------
__global__ void kW(const float* __restrict__ w1, float* __restrict__ w1T)
{
  int idx = blockIdx.x * 256 + threadIdx.x;
  if (idx < CIN * CH1) {
    int k = idx / CH1, t = idx % CH1;
    w1T[idx] = w1[(size_t)t * CIN + k];
  }
}

// ---------------- binning: count / scan / scatter ----------------
__global__ void kCount(const float* __restrict__ sup_xyz, int* __restrict__ counts)
{
  int i = blockIdx.x * 256 + threadIdx.x;
  if (i < N_SUP) {
    float x = sup_xyz[3*i], y = sup_xyz[3*i+1];
    atomicAdd(&counts[binOf(x) * NB + binOf(y)], 1);
  }
}

__global__ void kScan(const int* __restrict__ counts, int* __restrict__ starts, int* __restrict__ cursor)
{
  __shared__ int sc[NB*NB];
  int t = threadIdx.x;
  if (t < NB*NB) sc[t] = counts[t];
  __syncthreads();
  if (t == 0) {
    int acc = 0;
    for (int b = 0; b < NB*NB; b++) { int c = sc[b]; sc[b] = acc; acc += c; }
  }
  __syncthreads();
  if (t < NB*NB) { starts[t] = sc[t]; cursor[t] = sc[t]; }
  if (t == NB*NB) starts[NB*NB] = N_SUP;
}

__global__ void kScatter(const float* __restrict__ sup_xyz, int* __restrict__ cursor,
                         float* __restrict__ xs, float* __restrict__ ys,
                         float* __restrict__ zs, int* __restrict__ sid)
{
  int i = blockIdx.x * 256 + threadIdx.x;
  if (i < N_SUP) {
    float x = sup_xyz[3*i], y = sup_xyz[3*i+1], z = sup_xyz[3*i+2];
    int b = binOf(x) * NB + binOf(y);
    int p = atomicAdd(&cursor[b], 1);
    xs[p] = x; ys[p] = y; zs[p] = z; sid[p] = i;
  }
}

// ---------------- Kernel A12: bin-pruned cube filter + per-voxel 3NN ----------------
__global__ __launch_bounds__(256) void kA12(const float* __restrict__ xs,
                                            const float* __restrict__ ys,
                                            const float* __restrict__ zs,
                                            const int*   __restrict__ sid,
                                            const int*   __restrict__ starts,
                                            const float* __restrict__ new_xyz,
                                            float* __restrict__ nnW,
                                            int*   __restrict__ nnGI,
                                            float* __restrict__ nnLX)
{
  __shared__ float cxl[CAP], cyl[CAP], czl[CAP];
  __shared__ unsigned short cil[CAP];
  __shared__ int s_cnt;

  const int m   = blockIdx.x;
  const int tid = threadIdx.x;
  if (tid == 0) s_cnt = 0;
  __syncthreads();

  const float qx = new_xyz[m*3+0];
  const float qy = new_xyz[m*3+1];
  const float qz = new_xyz[m*3+2];

  // ---- phase 1: cube filter over <=3x3 bins (z-test vacuous: |dz|<4 always) ----
  const int bx0 = binOf(qx - 4.0f), bx1 = binOf(qx + 4.0f);
  const int by0 = binOf(qy - 4.0f), by1 = binOf(qy + 4.0f);
  for (int bx = bx0; bx <= bx1; bx++) {
    const int beg = starts[bx * NB + by0];
    const int end = starts[bx * NB + by1 + 1];
    for (int i = beg + tid; i < end; i += 256) {
      float x = xs[i], y = ys[i];
      if (fabsf(__fsub_rn(x, qx)) <= 4.0f && fabsf(__fsub_rn(y, qy)) <= 4.0f) {
        int p = atomicAdd(&s_cnt, 1);
        if (p < CAP) { cxl[p] = x; cyl[p] = y; czl[p] = zs[i]; cil[p] = (unsigned short)sid[i]; }
      }
    }
  }
  __syncthreads();
  const int cnt = (s_cnt < CAP) ? s_cnt : CAP;

  // ---- phase 2: per-voxel top-3 (one wave per voxel, round-robin) ----
  const int wv = tid >> 6, lane = tid & 63;
  for (int v = wv; v < TV; v += 4) {
    const int ix = v / 9, iy = (v / 3) % 3, iz = v % 3;
    const float gx = qx + gsel(ix);
    const float gy = qy + gsel(iy);
    const float gz = qz + gsel(iz);

    float d0 = 1e30f, d1 = 1e30f, d2 = 1e30f;
    int   i0 = 0x7fffffff, i1 = 0x7fffffff, i2 = 0x7fffffff;
    int   s0 = 0, s1 = 0, s2 = 0;

    for (int c = lane; c < cnt; c += 64) {
      float dx = __fsub_rn(gx, cxl[c]);
      float dy = __fsub_rn(gy, cyl[c]);
      float dz = __fsub_rn(gz, czl[c]);
      // forbid FMA contraction: must match numpy f32 (mul, mul, add, mul, add)
      float dd = __fadd_rn(__fadd_rn(__fmul_rn(dx,dx), __fmul_rn(dy,dy)), __fmul_rn(dz,dz));
      int gi = (int)cil[c];
      ins3(dd, gi, c, d0,i0,s0, d1,i1,s1, d2,i2,s2);
    }
    // butterfly merge across the 64 lanes
    for (int off = 32; off > 0; off >>= 1) {
      float od0 = __shfl_xor(d0, off, 64);
      float od1 = __shfl_xor(d1, off, 64);
      float od2 = __shfl_xor(d2, off, 64);
      int   oi0 = __shfl_xor(i0, off, 64);
      int   oi1 = __shfl_xor(i1, off, 64);
      int   oi2 = __shfl_xor(i2, off, 64);
      int   os0 = __shfl_xor(s0, off, 64);
      int   os1 = __shfl_xor(s1, off, 64);
      int   os2 = __shfl_xor(s2, off, 64);
      ins3(od0, oi0, os0, d0,i0,s0, d1,i1,s1, d2,i2,s2);
      ins3(od1, oi1, os1, d0,i0,s0, d1,i1,s1, d2,i2,s2);
      ins3(od2, oi2, os2, d0,i0,s0, d1,i1,s1, d2,i2,s2);
    }
    if (lane == 0) {
      const int base = m * TV + v;
      if (cnt > 0) {
        float dd0 = (d0 >= 1e29f) ? 1e10f : d0;
        float dd1 = (d1 >= 1e29f) ? 1e10f : d1;
        float dd2 = (d2 >= 1e29f) ? 1e10f : d2;
        float r0 = 1.0f / (dd0 + 1e-8f);
        float r1 = 1.0f / (dd1 + 1e-8f);
        float r2 = 1.0f / (dd2 + 1e-8f);
        float den = fmaxf(r0 + r1 + r2, 1e-8f);
        nnW[base*3+0] = r0 / den; nnW[base*3+1] = r1 / den; nnW[base*3+2] = r2 / den;
        nnGI[base*3+0] = (i0 < N_SUP) ? i0 : 0;
        nnGI[base*3+1] = (i1 < N_SUP) ? i1 : 0;
        nnGI[base*3+2] = (i2 < N_SUP) ? i2 : 0;
        const int sl[3] = {s0, s1, s2};
        #pragma unroll
        for (int k = 0; k < 3; k++) {
          nnLX[base*9 + k*3 + 0] = gx - cxl[sl[k]];
          nnLX[base*9 + k*3 + 1] = gy - cyl[sl[k]];
          nnLX[base*9 + k*3 + 2] = gz - czl[sl[k]];
        }
      } else {
        #pragma unroll
        for (int k = 0; k < 3; k++) {
          nnW[base*3+k] = 0.0f; nnGI[base*3+k] = 0;
          nnLX[base*9+k*3+0] = 0.0f; nnLX[base*9+k*3+1] = 0.0f; nnLX[base*9+k*3+2] = 0.0f;
        }
      }
    }
  }
}

// ---------------- Kernel A3: interp features + grouped conv1 ----------------
__global__ __launch_bounds__(256) void kA3(const float* __restrict__ sup_feat,
                                           const float* __restrict__ nnW,
                                           const int*   __restrict__ nnGI,
                                           const float* __restrict__ nnLX,
                                           const float* __restrict__ w1T,
                                           float* __restrict__ y1)
{
  __shared__ float s_feats[TV][CIN];
  __shared__ float s_w[TV][3];
  __shared__ int   s_gi[TV][3];

  const int m   = blockIdx.x;
  const int tid = threadIdx.x;

  for (int t = tid; t < TV*3; t += 256) {
    s_w[t/3][t%3]  = nnW[m*TV*3 + t];
    s_gi[t/3][t%3] = nnGI[m*TV*3 + t];
  }
  for (int t = tid; t < TV*9; t += 256) {
    s_feats[t/9][32 + t%9] = nnLX[m*TV*9 + t];
  }
  __syncthreads();

  for (int t = tid; t < TV*32; t += 256) {
    const int v = t >> 5, ch = t & 31;
    s_feats[v][ch] = s_w[v][0] * sup_feat[s_gi[v][0]*32 + ch]
                   + s_w[v][1] * sup_feat[s_gi[v][1]*32 + ch]
                   + s_w[v][2] * sup_feat[s_gi[v][2]*32 + ch];
  }
  __syncthreads();

  for (int t = tid; t < CH1; t += 256) {
    const int v = t >> 5;
    float acc = 0.0f;
    #pragma unroll
    for (int k = 0; k < CIN; k++) acc += s_feats[v][k] * w1T[k * CH1 + t];
    y1[(size_t)m * CH1 + t] = acc;
  }
}

// ---------------- Kernel B: BN1 stats (sum, sumsq per channel over M) ----------------
__global__ void kB(const float* __restrict__ y1, float* __restrict__ stats1)
{
  const int c  = threadIdx.x;        // 864 threads
  const int m0 = blockIdx.x * 256;   // 16 blocks
  float s = 0.0f, ss = 0.0f;
  for (int r = 0; r < 256; r++) {
    float v = y1[(size_t)(m0 + r) * CH1 + c];
    s += v; ss += v * v;
  }
  atomicAdd(&stats1[c],       s);
  atomicAdd(&stats1[CH1 + c], ss);
}

// ---------------- Kernel T: transpose w2 (128x864 f32) -> w2T (864x128 f32) ----------------
__global__ void kT(const float* __restrict__ w2, float* __restrict__ w2T)
{
  int t = blockIdx.x * 256 + threadIdx.x;
  if (t < CH1 * CH2) {
    int k = t / CH2, c = t % CH2;
    w2T[t] = w2[(size_t)c * CH1 + k];
  }
}

// ---------------- Kernel C: BN1 apply + ReLU + GEMM + BN2 partial stats ----------------
__global__ __launch_bounds__(256) void kC(const float* __restrict__ y1,
                                          const float* __restrict__ stats1,
                                          const float* __restrict__ g1,
                                          const float* __restrict__ b1,
                                          const float* __restrict__ w2T,
                                          float* __restrict__ z,
                                          float* __restrict__ stats2)
{
  __shared__ float yn[16][CH1];
  __shared__ float scs[CH1], shs[CH1];
  const int tid = threadIdx.x;
  const int m0  = blockIdx.x * 16;

  for (int c = tid; c < CH1; c += 256) {
    float s  = stats1[c], ssq = stats1[CH1 + c];
    float mu  = s  * (1.0f / M_Q);
    float var = ssq * (1.0f / M_Q) - mu * mu;
    float r   = 1.0f / sqrtf(var + 1e-5f);
    float gg = g1[c], bb = b1[c];
    scs[c] = r * gg;
    shs[c] = bb - mu * r * gg;
  }
  __syncthreads();

  for (int t = tid; t < 16 * CH1; t += 256) {
    int rr = t / CH1, c = t % CH1;
    float v = y1[(size_t)(m0 + rr) * CH1 + c];
    yn[rr][c] = fmaxf(v * scs[c] + shs[c], 0.0f);
  }
  __syncthreads();

  const int c = tid & 127, rg = tid >> 7;
  float acc[8];
  #pragma unroll
  for (int r = 0; r < 8; r++) acc[r] = 0.0f;

  for (int k = 0; k < CH1; k++) {
    float wv = w2T[(size_t)k * CH2 + c];
    #pragma unroll
    for (int r = 0; r < 8; r++) acc[r] += yn[rg*8 + r][k] * wv;
  }

  float s = 0.0f, ss = 0.0f;
  #pragma unroll
  for (int r = 0; r < 8; r++) {
    z[(size_t)(m0 + rg*8 + r) * CH2 + c] = acc[r];
    s += acc[r]; ss += acc[r] * acc[r];
  }
  atomicAdd(&stats2[c],       s);
  atomicAdd(&stats2[CH2 + c], ss);
}

// ---------------- Kernel D: BN2 apply + ReLU -> f32 out ----------------
__global__ void kD(const float* __restrict__ z,
                   const float* __restrict__ stats2,
                   const float* __restrict__ g2,
                   const float* __restrict__ b2,
                   float* __restrict__ out)
{
  int t = blockIdx.x * 256 + threadIdx.x;
  if (t >= M_Q * CH2) return;
  int c = t & 127;
  float s  = stats2[c], ssq = stats2[CH2 + c];
  float mu  = s  * (1.0f / M_Q);
  float var = ssq * (1.0f / M_Q) - mu * mu;
  float r   = 1.0f / sqrtf(var + 1e-5f);
  float val = fmaxf((z[t] - mu) * r * g2[c] + b2[c], 0.0f);
  out[t] = val;
}

extern "C" void kernel_launch(void* const* d_in, const int* in_sizes, int n_in,
                              void* d_out, int out_size, void* d_ws, size_t ws_size,
                              hipStream_t stream)
{
  const float* sup_xyz  = (const float*)d_in[0];
  const float* sup_feat = (const float*)d_in[1];
  const float* new_xyz  = (const float*)d_in[2];
  const float* w1       = (const float*)d_in[3];
  const float* g1       = (const float*)d_in[4];
  const float* b1       = (const float*)d_in[5];
  const float* w2       = (const float*)d_in[6];
  const float* g2       = (const float*)d_in[7];
  const float* b2       = (const float*)d_in[8];
  float* out = (float*)d_out;

  char* ws = (char*)d_ws;
  float* y1     = (float*)(ws);                       // 14,155,776 B
  float* z      = (float*)(ws + 14155776);            //  2,097,152 B (aliased by w1T early)
  float* w2T    = (float*)(ws + 16252928);            //    442,368 B
  float* stats  = (float*)(ws + 16695296);            //      7,936 B (1984 f32)
  int*   counts = (int*)  (ws + 16703232);            //        576 B
  int*   cursor = (int*)  (ws + 16703808);            //        576 B
  int*   starts = (int*)  (ws + 16704384);            //        580 B
  float* xs     = (float*)(ws + 16704964);            //     65,536 B
  float* ys     = (float*)(ws + 16770500);
  float* zs     = (float*)(ws + 16836036);
  int*   sid    = (int*)  (ws + 16901572);
  float* nnW    = (float*)(ws + 16967108);            //  1,327,104 B
  int*   nnGI   = (int*)  (ws + 18294212);            //  1,327,104 B
  float* nnLX   = (float*)(ws + 19621316);            //  3,981,312 B  (end 23,602,628)
  float* stats1 = stats;
  float* stats2 = stats + 2 * CH1;
  // w1T (141,696 B) aliases z: kA3 (last reader) runs before kC (writer of z).
  float* w1T    = z;

  // zero stats + counts + cursor in one contiguous memset
  hipMemsetAsync(stats, 0, 7936 + 576 + 576, stream);

  hipLaunchKernelGGL(kW,      dim3((CIN*CH1 + 255) / 256), dim3(256), 0, stream, w1, w1T);
  hipLaunchKernelGGL(kCount,  dim3((N_SUP + 255) / 256),   dim3(256), 0, stream, sup_xyz, counts);
  hipLaunchKernelGGL(kScan,   dim3(1),                     dim3(256), 0, stream, counts, starts, cursor);
  hipLaunchKernelGGL(kScatter,dim3((N_SUP + 255) / 256),   dim3(256), 0, stream, sup_xyz, cursor, xs, ys, zs, sid);
  hipLaunchKernelGGL(kA12,    dim3(M_Q),                   dim3(256), 0, stream, xs, ys, zs, sid, starts, new_xyz, nnW, nnGI, nnLX);
  hipLaunchKernelGGL(kA3,     dim3(M_Q),                   dim3(256), 0, stream, sup_feat, nnW, nnGI, nnLX, w1T, y1);
  hipLaunchKernelGGL(kB,      dim3(16),                    dim3(CH1), 0, stream, y1, stats1);
  hipLaunchKernelGGL(kT,      dim3((CH1*CH2 + 255) / 256), dim3(256), 0, stream, w2, w2T);
  hipLaunchKernelGGL(kC,      dim3(M_Q / 16),              dim3(256), 0, stream, y1, stats1, g1, b1, w2T, z, stats2);
  hipLaunchKernelGGL(kD,      dim3((M_Q*CH2 + 255) / 256), dim3(256), 0, stream, z, stats2, g2, b2, out);
}

// Round 5
// 195.910 us; speedup vs baseline: 5.1780x; 5.0160x over previous
//
#include <hip/hip_runtime.h>
#include <hip/hip_bf16.h>

#define N_SUP 16384
#define M_Q   4096
#define TV    27
#define CIN   41
#define CH1   864
#define CH2   128
#define CAP   1024
#define NB    12          // bins per xy axis (width 50/12 = 4.17 >= 4)

// grid offset value for axis-index 0/1/2 : linspace(-R+R/NV, R-R/NV, 3) = {-1.3333334, 0, +1.3333334}
__device__ __forceinline__ float gsel(int i){
  const float GOFF = (float)(-2.0 + 2.0 / 3.0);   // -1.3333334f (matches f32 linspace endpoint)
  return (i == 0) ? GOFF : ((i == 2) ? -GOFF : 0.0f);
}

// monotone bin map, identical for points and queries (monotonicity is all correctness needs)
__device__ __forceinline__ int binOf(float x){
  int b = (int)(x * (float)(NB / 50.0));
  return (b < 0) ? 0 : ((b > NB - 1) ? NB - 1 : b);
}

// branchless 3-deep insert of u64 key (keeps k0 <= k1 <= k2)
__device__ __forceinline__ void insK(unsigned long long key,
                                     unsigned long long& k0,
                                     unsigned long long& k1,
                                     unsigned long long& k2){
  bool b0 = key < k0, b1 = key < k1, b2 = key < k2;
  k2 = b1 ? k1 : (b2 ? key : k2);
  k1 = b0 ? k0 : (b1 ? key : k1);
  k0 = b0 ? key : k0;
}

// ---------------- Kernel W: transpose w1 [864][41] -> w1T [41][864] ----------------
__global__ void kW(const float* __restrict__ w1, float* __restrict__ w1T)
{
  int idx = blockIdx.x * 256 + threadIdx.x;
  if (idx < CIN * CH1) {
    int k = idx / CH1, t = idx % CH1;
    w1T[idx] = w1[(size_t)t * CIN + k];
  }
}

// ---------------- binning: count / scan / scatter ----------------
__global__ void kCount(const float* __restrict__ sup_xyz, int* __restrict__ counts)
{
  int i = blockIdx.x * 256 + threadIdx.x;
  if (i < N_SUP) {
    float x = sup_xyz[3*i], y = sup_xyz[3*i+1];
    atomicAdd(&counts[binOf(x) * NB + binOf(y)], 1);
  }
}

__global__ void kScan(const int* __restrict__ counts, int* __restrict__ starts, int* __restrict__ cursor)
{
  __shared__ int sc[NB*NB];
  int t = threadIdx.x;
  if (t < NB*NB) sc[t] = counts[t];
  __syncthreads();
  if (t == 0) {
    int acc = 0;
    for (int b = 0; b < NB*NB; b++) { int c = sc[b]; sc[b] = acc; acc += c; }
  }
  __syncthreads();
  if (t < NB*NB) { starts[t] = sc[t]; cursor[t] = sc[t]; }
  if (t == NB*NB) starts[NB*NB] = N_SUP;
}

__global__ void kScatter(const float* __restrict__ sup_xyz, int* __restrict__ cursor,
                         float* __restrict__ xs, float* __restrict__ ys,
                         float* __restrict__ zs, int* __restrict__ sid)
{
  int i = blockIdx.x * 256 + threadIdx.x;
  if (i < N_SUP) {
    float x = sup_xyz[3*i], y = sup_xyz[3*i+1], z = sup_xyz[3*i+2];
    int b = binOf(x) * NB + binOf(y);
    int p = atomicAdd(&cursor[b], 1);
    xs[p] = x; ys[p] = y; zs[p] = z; sid[p] = i;
  }
}

// ---------------- Kernel A12: bin-pruned cube filter + per-voxel 3NN ----------------
// Phase 2: 8 threads per voxel scan stride-8 candidate slices holding private
// top-3 as packed u64 keys [d_bits:32 | gi:14 | slot:10] (u64 order == (d, gi)
// lexicographic == jax.lax.top_k tie-break). No cross-lane shuffles at all.
__global__ __launch_bounds__(256) void kA12(const float* __restrict__ xs,
                                            const float* __restrict__ ys,
                                            const float* __restrict__ zs,
                                            const int*   __restrict__ sid,
                                            const int*   __restrict__ starts,
                                            const float* __restrict__ new_xyz,
                                            float* __restrict__ nnW,
                                            int*   __restrict__ nnGI,
                                            float* __restrict__ nnLX)
{
  __shared__ float4 cxyz[CAP];
  __shared__ unsigned long long sk[TV][8][3];
  __shared__ int s_cnt;

  const int m   = blockIdx.x;
  const int tid = threadIdx.x;
  if (tid == 0) s_cnt = 0;
  __syncthreads();

  const float qx = new_xyz[m*3+0];
  const float qy = new_xyz[m*3+1];
  const float qz = new_xyz[m*3+2];

  // ---- phase 1: cube filter over <=3x3 bins (z-test vacuous: |dz|<4 always) ----
  const int bx0 = binOf(qx - 4.0f), bx1 = binOf(qx + 4.0f);
  const int by0 = binOf(qy - 4.0f), by1 = binOf(qy + 4.0f);
  for (int bx = bx0; bx <= bx1; bx++) {
    const int beg = starts[bx * NB + by0];
    const int end = starts[bx * NB + by1 + 1];
    for (int i = beg + tid; i < end; i += 256) {
      float x = xs[i], y = ys[i];
      if (fabsf(__fsub_rn(x, qx)) <= 4.0f && fabsf(__fsub_rn(y, qy)) <= 4.0f) {
        int p = atomicAdd(&s_cnt, 1);
        if (p < CAP) cxyz[p] = make_float4(x, y, zs[i], __uint_as_float((unsigned)sid[i]));
      }
    }
  }
  __syncthreads();
  const int cnt = (s_cnt < CAP) ? s_cnt : CAP;

  // ---- phase 2a: strided scan, 8 threads per voxel ----
  const int v = tid >> 3, j = tid & 7;
  if (v < TV) {
    const float gx = qx + gsel(v / 9);
    const float gy = qy + gsel((v / 3) % 3);
    const float gz = qz + gsel(v % 3);
    unsigned long long k0 = ~0ull, k1 = ~0ull, k2 = ~0ull;
    for (int c = j; c < cnt; c += 8) {
      float4 f4 = cxyz[c];
      float dx = __fsub_rn(gx, f4.x);
      float dy = __fsub_rn(gy, f4.y);
      float dz = __fsub_rn(gz, f4.z);
      // forbid FMA contraction: must match numpy f32 (mul, mul, add, mul, add)
      float dd = __fadd_rn(__fadd_rn(__fmul_rn(dx,dx), __fmul_rn(dy,dy)), __fmul_rn(dz,dz));
      unsigned long long key = ((unsigned long long)__float_as_uint(dd) << 32)
                             | ((unsigned long long)__float_as_uint(f4.w) << 10)
                             | (unsigned long long)(unsigned)c;
      insK(key, k0, k1, k2);
    }
    sk[v][j][0] = k0; sk[v][j][1] = k1; sk[v][j][2] = k2;
  }
  __syncthreads();

  // ---- phase 2b: merge 8x3 keys per voxel + emit (threads 0..26) ----
  if (tid < TV) {
    const int vv = tid;
    const float gx = qx + gsel(vv / 9);
    const float gy = qy + gsel((vv / 3) % 3);
    const float gz = qz + gsel(vv % 3);
    unsigned long long k0 = ~0ull, k1 = ~0ull, k2 = ~0ull;
    #pragma unroll
    for (int jj = 0; jj < 8; jj++) {
      insK(sk[vv][jj][0], k0, k1, k2);
      insK(sk[vv][jj][1], k0, k1, k2);
      insK(sk[vv][jj][2], k0, k1, k2);
    }
    const int base = m * TV + vv;
    if (cnt > 0) {
      unsigned long long ks[3] = {k0, k1, k2};
      float d[3]; int gi[3]; int sl[3]; bool ok[3];
      #pragma unroll
      for (int r = 0; r < 3; r++) {
        unsigned db = (unsigned)(ks[r] >> 32);
        ok[r] = (db != 0xFFFFFFFFu);
        d[r]  = ok[r] ? __uint_as_float(db) : 1e10f;
        gi[r] = ok[r] ? (int)((ks[r] >> 10) & 0x3FFFull) : 0;
        sl[r] = (int)(ks[r] & 0x3FFull);
      }
      float r0 = 1.0f / (d[0] + 1e-8f);
      float r1 = 1.0f / (d[1] + 1e-8f);
      float r2 = 1.0f / (d[2] + 1e-8f);
      float den = fmaxf(r0 + r1 + r2, 1e-8f);
      nnW[base*3+0] = r0 / den; nnW[base*3+1] = r1 / den; nnW[base*3+2] = r2 / den;
      nnGI[base*3+0] = gi[0]; nnGI[base*3+1] = gi[1]; nnGI[base*3+2] = gi[2];
      #pragma unroll
      for (int r = 0; r < 3; r++) {
        if (ok[r]) {
          float4 f4 = cxyz[sl[r]];
          nnLX[base*9 + r*3 + 0] = gx - f4.x;
          nnLX[base*9 + r*3 + 1] = gy - f4.y;
          nnLX[base*9 + r*3 + 2] = gz - f4.z;
        } else {
          nnLX[base*9 + r*3 + 0] = 0.0f;
          nnLX[base*9 + r*3 + 1] = 0.0f;
          nnLX[base*9 + r*3 + 2] = 0.0f;
        }
      }
    } else {
      #pragma unroll
      for (int r = 0; r < 3; r++) {
        nnW[base*3+r] = 0.0f; nnGI[base*3+r] = 0;
        nnLX[base*9+r*3+0] = 0.0f; nnLX[base*9+r*3+1] = 0.0f; nnLX[base*9+r*3+2] = 0.0f;
      }
    }
  }
}

// ---------------- Kernel A3: interp features + grouped conv1 ----------------
__global__ __launch_bounds__(256) void kA3(const float* __restrict__ sup_feat,
                                           const float* __restrict__ nnW,
                                           const int*   __restrict__ nnGI,
                                           const float* __restrict__ nnLX,
                                           const float* __restrict__ w1T,
                                           float* __restrict__ y1)
{
  __shared__ float s_feats[TV][CIN];
  __shared__ float s_w[TV][3];
  __shared__ int   s_gi[TV][3];

  const int m   = blockIdx.x;
  const int tid = threadIdx.x;

  for (int t = tid; t < TV*3; t += 256) {
    s_w[t/3][t%3]  = nnW[m*TV*3 + t];
    s_gi[t/3][t%3] = nnGI[m*TV*3 + t];
  }
  for (int t = tid; t < TV*9; t += 256) {
    s_feats[t/9][32 + t%9] = nnLX[m*TV*9 + t];
  }
  __syncthreads();

  for (int t = tid; t < TV*32; t += 256) {
    const int v = t >> 5, ch = t & 31;
    s_feats[v][ch] = s_w[v][0] * sup_feat[s_gi[v][0]*32 + ch]
                   + s_w[v][1] * sup_feat[s_gi[v][1]*32 + ch]
                   + s_w[v][2] * sup_feat[s_gi[v][2]*32 + ch];
  }
  __syncthreads();

  for (int t = tid; t < CH1; t += 256) {
    const int v = t >> 5;
    float acc = 0.0f;
    #pragma unroll
    for (int k = 0; k < CIN; k++) acc += s_feats[v][k] * w1T[k * CH1 + t];
    y1[(size_t)m * CH1 + t] = acc;
  }
}

// ---------------- Kernel B: BN1 stats (sum, sumsq per channel over M) ----------------
__global__ void kB(const float* __restrict__ y1, float* __restrict__ stats1)
{
  const int c  = threadIdx.x;        // 864 threads
  const int m0 = blockIdx.x * 256;   // 16 blocks
  float s = 0.0f, ss = 0.0f;
  for (int r = 0; r < 256; r++) {
    float v = y1[(size_t)(m0 + r) * CH1 + c];
    s += v; ss += v * v;
  }
  atomicAdd(&stats1[c],       s);
  atomicAdd(&stats1[CH1 + c], ss);
}

// ---------------- Kernel T: transpose w2 (128x864 f32) -> w2T (864x128 f32) ----------------
__global__ void kT(const float* __restrict__ w2, float* __restrict__ w2T)
{
  int t = blockIdx.x * 256 + threadIdx.x;
  if (t < CH1 * CH2) {
    int k = t / CH2, c = t % CH2;
    w2T[t] = w2[(size_t)c * CH1 + k];
  }
}

// ---------------- Kernel C: BN1 apply + ReLU + GEMM + BN2 partial stats ----------------
__global__ __launch_bounds__(256) void kC(const float* __restrict__ y1,
                                          const float* __restrict__ stats1,
                                          const float* __restrict__ g1,
                                          const float* __restrict__ b1,
                                          const float* __restrict__ w2T,
                                          float* __restrict__ z,
                                          float* __restrict__ stats2)
{
  __shared__ float yn[16][CH1];
  __shared__ float scs[CH1], shs[CH1];
  const int tid = threadIdx.x;
  const int m0  = blockIdx.x * 16;

  for (int c = tid; c < CH1; c += 256) {
    float s  = stats1[c], ssq = stats1[CH1 + c];
    float mu  = s  * (1.0f / M_Q);
    float var = ssq * (1.0f / M_Q) - mu * mu;
    float r   = 1.0f / sqrtf(var + 1e-5f);
    float gg = g1[c], bb = b1[c];
    scs[c] = r * gg;
    shs[c] = bb - mu * r * gg;
  }
  __syncthreads();

  for (int t = tid; t < 16 * CH1; t += 256) {
    int rr = t / CH1, c = t % CH1;
    float v = y1[(size_t)(m0 + rr) * CH1 + c];
    yn[rr][c] = fmaxf(v * scs[c] + shs[c], 0.0f);
  }
  __syncthreads();

  const int c = tid & 127, rg = tid >> 7;
  float acc[8];
  #pragma unroll
  for (int r = 0; r < 8; r++) acc[r] = 0.0f;

  for (int k = 0; k < CH1; k++) {
    float wv = w2T[(size_t)k * CH2 + c];
    #pragma unroll
    for (int r = 0; r < 8; r++) acc[r] += yn[rg*8 + r][k] * wv;
  }

  float s = 0.0f, ss = 0.0f;
  #pragma unroll
  for (int r = 0; r < 8; r++) {
    z[(size_t)(m0 + rg*8 + r) * CH2 + c] = acc[r];
    s += acc[r]; ss += acc[r] * acc[r];
  }
  atomicAdd(&stats2[c],       s);
  atomicAdd(&stats2[CH2 + c], ss);
}

// ---------------- Kernel D: BN2 apply + ReLU -> f32 out ----------------
__global__ void kD(const float* __restrict__ z,
                   const float* __restrict__ stats2,
                   const float* __restrict__ g2,
                   const float* __restrict__ b2,
                   float* __restrict__ out)
{
  int t = blockIdx.x * 256 + threadIdx.x;
  if (t >= M_Q * CH2) return;
  int c = t & 127;
  float s  = stats2[c], ssq = stats2[CH2 + c];
  float mu  = s  * (1.0f / M_Q);
  float var = ssq * (1.0f / M_Q) - mu * mu;
  float r   = 1.0f / sqrtf(var + 1e-5f);
  float val = fmaxf((z[t] - mu) * r * g2[c] + b2[c], 0.0f);
  out[t] = val;
}

extern "C" void kernel_launch(void* const* d_in, const int* in_sizes, int n_in,
                              void* d_out, int out_size, void* d_ws, size_t ws_size,
                              hipStream_t stream)
{
  const float* sup_xyz  = (const float*)d_in[0];
  const float* sup_feat = (const float*)d_in[1];
  const float* new_xyz  = (const float*)d_in[2];
  const float* w1       = (const float*)d_in[3];
  const float* g1       = (const float*)d_in[4];
  const float* b1       = (const float*)d_in[5];
  const float* w2       = (const float*)d_in[6];
  const float* g2       = (const float*)d_in[7];
  const float* b2       = (const float*)d_in[8];
  float* out = (float*)d_out;

  char* ws = (char*)d_ws;
  float* y1     = (float*)(ws);                       // 14,155,776 B
  float* z      = (float*)(ws + 14155776);            //  2,097,152 B (aliased by w1T early)
  float* w2T    = (float*)(ws + 16252928);            //    442,368 B
  float* stats  = (float*)(ws + 16695296);            //      7,936 B (1984 f32)
  int*   counts = (int*)  (ws + 16703232);            //        576 B
  int*   cursor = (int*)  (ws + 16703808);            //        576 B
  int*   starts = (int*)  (ws + 16704384);            //        580 B
  float* xs     = (float*)(ws + 16704964);            //     65,536 B
  float* ys     = (float*)(ws + 16770500);
  float* zs     = (float*)(ws + 16836036);
  int*   sid    = (int*)  (ws + 16901572);
  float* nnW    = (float*)(ws + 16967108);            //  1,327,104 B
  int*   nnGI   = (int*)  (ws + 18294212);            //  1,327,104 B
  float* nnLX   = (float*)(ws + 19621316);            //  3,981,312 B  (end 23,602,628)
  float* stats1 = stats;
  float* stats2 = stats + 2 * CH1;
  // w1T (141,696 B) aliases z: kA3 (last reader) runs before kC (writer of z).
  float* w1T    = z;

  // zero stats + counts + cursor in one contiguous memset
  hipMemsetAsync(stats, 0, 7936 + 576 + 576, stream);

  hipLaunchKernelGGL(kW,      dim3((CIN*CH1 + 255) / 256), dim3(256), 0, stream, w1, w1T);
  hipLaunchKernelGGL(kCount,  dim3((N_SUP + 255) / 256),   dim3(256), 0, stream, sup_xyz, counts);
  hipLaunchKernelGGL(kScan,   dim3(1),                     dim3(256), 0, stream, counts, starts, cursor);
  hipLaunchKernelGGL(kScatter,dim3((N_SUP + 255) / 256),   dim3(256), 0, stream, sup_xyz, cursor, xs, ys, zs, sid);
  hipLaunchKernelGGL(kA12,    dim3(M_Q),                   dim3(256), 0, stream, xs, ys, zs, sid, starts, new_xyz, nnW, nnGI, nnLX);
  hipLaunchKernelGGL(kA3,     dim3(M_Q),                   dim3(256), 0, stream, sup_feat, nnW, nnGI, nnLX, w1T, y1);
  hipLaunchKernelGGL(kB,      dim3(16),                    dim3(CH1), 0, stream, y1, stats1);
  hipLaunchKernelGGL(kT,      dim3((CH1*CH2 + 255) / 256), dim3(256), 0, stream, w2, w2T);
  hipLaunchKernelGGL(kC,      dim3(M_Q / 16),              dim3(256), 0, stream, y1, stats1, g1, b1, w2T, z, stats2);
  hipLaunchKernelGGL(kD,      dim3((M_Q*CH2 + 255) / 256), dim3(256), 0, stream, z, stats2, g2, b2, out);
}

// Round 6
// 184.720 us; speedup vs baseline: 5.4917x; 1.0606x over previous
//
#include <hip/hip_runtime.h>
#include <hip/hip_bf16.h>

#define N_SUP 16384
#define M_Q   4096
#define TV    27
#define CIN   41
#define CH1   864
#define CH2   128
#define CAP   1024
#define NB    12          // bins per xy axis (width 50/12 = 4.17 >= 4)

// grid offset value for axis-index 0/1/2 : linspace(-R+R/NV, R-R/NV, 3) = {-1.3333334, 0, +1.3333334}
__device__ __forceinline__ float gsel(int i){
  const float GOFF = (float)(-2.0 + 2.0 / 3.0);   // -1.3333334f (matches f32 linspace endpoint)
  return (i == 0) ? GOFF : ((i == 2) ? -GOFF : 0.0f);
}

// monotone bin map, identical for points and queries (monotonicity is all correctness needs)
__device__ __forceinline__ int binOf(float x){
  int b = (int)(x * (float)(NB / 50.0));
  return (b < 0) ? 0 : ((b > NB - 1) ? NB - 1 : b);
}

// branchless 3-deep insert of u64 key (keeps k0 <= k1 <= k2)
__device__ __forceinline__ void insK(unsigned long long key,
                                     unsigned long long& k0,
                                     unsigned long long& k1,
                                     unsigned long long& k2){
  bool b0 = key < k0, b1 = key < k1, b2 = key < k2;
  k2 = b1 ? k1 : (b2 ? key : k2);
  k1 = b0 ? k0 : (b1 ? key : k1);
  k0 = b0 ? key : k0;
}

// ---------------- Kernel WT: transpose w1 [864][41]->w1T [41][864] and w2 [128][864]->w2T [864][128]
__global__ void kWT(const float* __restrict__ w1, float* __restrict__ w1T,
                    const float* __restrict__ w2, float* __restrict__ w2T)
{
  int idx = blockIdx.x * 256 + threadIdx.x;
  if (idx < CIN * CH1) {
    int k = idx / CH1, t = idx % CH1;
    w1T[idx] = w1[(size_t)t * CIN + k];
  }
  int j = idx - CIN * CH1;
  if (j >= 0 && j < CH1 * CH2) {
    int k = j / CH2, c = j % CH2;
    w2T[j] = w2[(size_t)c * CH1 + k];
  }
}

// ---------------- binning: count / scan / scatter ----------------
__global__ void kCount(const float* __restrict__ sup_xyz, int* __restrict__ counts)
{
  int i = blockIdx.x * 256 + threadIdx.x;
  if (i < N_SUP) {
    float x = sup_xyz[3*i], y = sup_xyz[3*i+1];
    atomicAdd(&counts[binOf(x) * NB + binOf(y)], 1);
  }
}

__global__ void kScan(const int* __restrict__ counts, int* __restrict__ starts, int* __restrict__ cursor)
{
  __shared__ int sc[NB*NB];
  int t = threadIdx.x;
  if (t < NB*NB) sc[t] = counts[t];
  __syncthreads();
  if (t == 0) {
    int acc = 0;
    for (int b = 0; b < NB*NB; b++) { int c = sc[b]; sc[b] = acc; acc += c; }
  }
  __syncthreads();
  if (t < NB*NB) { starts[t] = sc[t]; cursor[t] = sc[t]; }
  if (t == NB*NB) starts[NB*NB] = N_SUP;
}

__global__ void kScatter(const float* __restrict__ sup_xyz, int* __restrict__ cursor,
                         float* __restrict__ xs, float* __restrict__ ys,
                         float* __restrict__ zs, int* __restrict__ sid)
{
  int i = blockIdx.x * 256 + threadIdx.x;
  if (i < N_SUP) {
    float x = sup_xyz[3*i], y = sup_xyz[3*i+1], z = sup_xyz[3*i+2];
    int b = binOf(x) * NB + binOf(y);
    int p = atomicAdd(&cursor[b], 1);
    xs[p] = x; ys[p] = y; zs[p] = z; sid[p] = i;
  }
}

// ---------------- Kernel A12: bin-pruned cube filter + per-voxel 3NN ----------------
__global__ __launch_bounds__(256) void kA12(const float* __restrict__ xs,
                                            const float* __restrict__ ys,
                                            const float* __restrict__ zs,
                                            const int*   __restrict__ sid,
                                            const int*   __restrict__ starts,
                                            const float* __restrict__ new_xyz,
                                            float* __restrict__ nnW,
                                            int*   __restrict__ nnGI,
                                            float* __restrict__ nnLX)
{
  __shared__ float4 cxyz[CAP];
  __shared__ unsigned long long sk[TV][8][3];
  __shared__ int s_cnt;

  const int m   = blockIdx.x;
  const int tid = threadIdx.x;
  if (tid == 0) s_cnt = 0;
  __syncthreads();

  const float qx = new_xyz[m*3+0];
  const float qy = new_xyz[m*3+1];
  const float qz = new_xyz[m*3+2];

  // ---- phase 1: cube filter over <=3x3 bins (z-test vacuous: |dz|<4 always) ----
  const int bx0 = binOf(qx - 4.0f), bx1 = binOf(qx + 4.0f);
  const int by0 = binOf(qy - 4.0f), by1 = binOf(qy + 4.0f);
  for (int bx = bx0; bx <= bx1; bx++) {
    const int beg = starts[bx * NB + by0];
    const int end = starts[bx * NB + by1 + 1];
    for (int i = beg + tid; i < end; i += 256) {
      float x = xs[i], y = ys[i];
      if (fabsf(__fsub_rn(x, qx)) <= 4.0f && fabsf(__fsub_rn(y, qy)) <= 4.0f) {
        int p = atomicAdd(&s_cnt, 1);
        if (p < CAP) cxyz[p] = make_float4(x, y, zs[i], __uint_as_float((unsigned)sid[i]));
      }
    }
  }
  __syncthreads();
  const int cnt = (s_cnt < CAP) ? s_cnt : CAP;

  // ---- phase 2a: strided scan, 8 threads per voxel ----
  const int v = tid >> 3, j = tid & 7;
  if (v < TV) {
    const float gx = qx + gsel(v / 9);
    const float gy = qy + gsel((v / 3) % 3);
    const float gz = qz + gsel(v % 3);
    unsigned long long k0 = ~0ull, k1 = ~0ull, k2 = ~0ull;
    for (int c = j; c < cnt; c += 8) {
      float4 f4 = cxyz[c];
      float dx = __fsub_rn(gx, f4.x);
      float dy = __fsub_rn(gy, f4.y);
      float dz = __fsub_rn(gz, f4.z);
      // forbid FMA contraction: must match numpy f32 (mul, mul, add, mul, add)
      float dd = __fadd_rn(__fadd_rn(__fmul_rn(dx,dx), __fmul_rn(dy,dy)), __fmul_rn(dz,dz));
      unsigned long long key = ((unsigned long long)__float_as_uint(dd) << 32)
                             | ((unsigned long long)__float_as_uint(f4.w) << 10)
                             | (unsigned long long)(unsigned)c;
      insK(key, k0, k1, k2);
    }
    sk[v][j][0] = k0; sk[v][j][1] = k1; sk[v][j][2] = k2;
  }
  __syncthreads();

  // ---- phase 2b: merge 8x3 keys per voxel + emit (threads 0..26) ----
  if (tid < TV) {
    const int vv = tid;
    const float gx = qx + gsel(vv / 9);
    const float gy = qy + gsel((vv / 3) % 3);
    const float gz = qz + gsel(vv % 3);
    unsigned long long k0 = ~0ull, k1 = ~0ull, k2 = ~0ull;
    #pragma unroll
    for (int jj = 0; jj < 8; jj++) {
      insK(sk[vv][jj][0], k0, k1, k2);
      insK(sk[vv][jj][1], k0, k1, k2);
      insK(sk[vv][jj][2], k0, k1, k2);
    }
    const int base = m * TV + vv;
    if (cnt > 0) {
      unsigned long long ks[3] = {k0, k1, k2};
      float d[3]; int gi[3]; int sl[3]; bool ok[3];
      #pragma unroll
      for (int r = 0; r < 3; r++) {
        unsigned db = (unsigned)(ks[r] >> 32);
        ok[r] = (db != 0xFFFFFFFFu);
        d[r]  = ok[r] ? __uint_as_float(db) : 1e10f;
        gi[r] = ok[r] ? (int)((ks[r] >> 10) & 0x3FFFull) : 0;
        sl[r] = (int)(ks[r] & 0x3FFull);
      }
      float r0 = 1.0f / (d[0] + 1e-8f);
      float r1 = 1.0f / (d[1] + 1e-8f);
      float r2 = 1.0f / (d[2] + 1e-8f);
      float den = fmaxf(r0 + r1 + r2, 1e-8f);
      nnW[base*3+0] = r0 / den; nnW[base*3+1] = r1 / den; nnW[base*3+2] = r2 / den;
      nnGI[base*3+0] = gi[0]; nnGI[base*3+1] = gi[1]; nnGI[base*3+2] = gi[2];
      #pragma unroll
      for (int r = 0; r < 3; r++) {
        if (ok[r]) {
          float4 f4 = cxyz[sl[r]];
          nnLX[base*9 + r*3 + 0] = gx - f4.x;
          nnLX[base*9 + r*3 + 1] = gy - f4.y;
          nnLX[base*9 + r*3 + 2] = gz - f4.z;
        } else {
          nnLX[base*9 + r*3 + 0] = 0.0f;
          nnLX[base*9 + r*3 + 1] = 0.0f;
          nnLX[base*9 + r*3 + 2] = 0.0f;
        }
      }
    } else {
      #pragma unroll
      for (int r = 0; r < 3; r++) {
        nnW[base*3+r] = 0.0f; nnGI[base*3+r] = 0;
        nnLX[base*9+r*3+0] = 0.0f; nnLX[base*9+r*3+1] = 0.0f; nnLX[base*9+r*3+2] = 0.0f;
      }
    }
  }
}

// ---------------- Kernel A3: interp features + grouped conv1, 8 queries per block ----------------
__global__ __launch_bounds__(256) void kA3(const float* __restrict__ sup_feat,
                                           const float* __restrict__ nnW,
                                           const int*   __restrict__ nnGI,
                                           const float* __restrict__ nnLX,
                                           const float* __restrict__ w1T,
                                           float* __restrict__ y1)
{
  __shared__ float s_feats[8][TV][CIN];   // 35,424 B
  __shared__ float s_w[8][TV][3];
  __shared__ int   s_gi[8][TV][3];

  const int m0  = blockIdx.x * 8;
  const int tid = threadIdx.x;

  for (int t = tid; t < 8*TV*3; t += 256) {
    int q = t / (TV*3), rem = t % (TV*3);
    s_w[q][rem/3][rem%3]  = nnW[m0*TV*3 + t];
    s_gi[q][rem/3][rem%3] = nnGI[m0*TV*3 + t];
  }
  for (int t = tid; t < 8*TV*9; t += 256) {
    int q = t / (TV*9), rem = t % (TV*9);
    s_feats[q][rem/9][32 + rem%9] = nnLX[m0*TV*9 + t];
  }
  __syncthreads();

  for (int t = tid; t < 8*TV*32; t += 256) {
    const int q = t / (TV*32), rem = t % (TV*32);
    const int v = rem >> 5, ch = rem & 31;
    s_feats[q][v][ch] = s_w[q][v][0] * sup_feat[s_gi[q][v][0]*32 + ch]
                      + s_w[q][v][1] * sup_feat[s_gi[q][v][1]*32 + ch]
                      + s_w[q][v][2] * sup_feat[s_gi[q][v][2]*32 + ch];
  }
  __syncthreads();

  for (int t = tid; t < CH1; t += 256) {
    const int v = t >> 5;
    float acc[8];
    #pragma unroll
    for (int q = 0; q < 8; q++) acc[q] = 0.0f;
    for (int k = 0; k < CIN; k++) {
      float w = w1T[k * CH1 + t];
      #pragma unroll
      for (int q = 0; q < 8; q++) acc[q] += s_feats[q][v][k] * w;
    }
    #pragma unroll
    for (int q = 0; q < 8; q++) y1[(size_t)(m0 + q) * CH1 + t] = acc[q];
  }
}

// ---------------- Kernel B: BN1 stats (sum, sumsq per channel over M) ----------------
__global__ void kB(const float* __restrict__ y1, float* __restrict__ stats1)
{
  const int c  = threadIdx.x;        // 864 threads
  const int m0 = blockIdx.x * 64;    // 64 blocks
  float s = 0.0f, ss = 0.0f;
  for (int r = 0; r < 64; r++) {
    float v = y1[(size_t)(m0 + r) * CH1 + c];
    s += v; ss += v * v;
  }
  atomicAdd(&stats1[c],       s);
  atomicAdd(&stats1[CH1 + c], ss);
}

// ---------------- Kernel C: BN1 apply + ReLU + GEMM (8 rows/block) + BN2 partial stats ----------------
__global__ __launch_bounds__(256) void kC(const float* __restrict__ y1,
                                          const float* __restrict__ stats1,
                                          const float* __restrict__ g1,
                                          const float* __restrict__ b1,
                                          const float* __restrict__ w2T,
                                          float* __restrict__ z,
                                          float* __restrict__ stats2)
{
  __shared__ float yn[8][CH1];        // 27,648 B
  __shared__ float scs[CH1], shs[CH1];
  const int tid = threadIdx.x;
  const int m0  = blockIdx.x * 8;

  for (int c = tid; c < CH1; c += 256) {
    float s  = stats1[c], ssq = stats1[CH1 + c];
    float mu  = s  * (1.0f / M_Q);
    float var = ssq * (1.0f / M_Q) - mu * mu;
    float r   = 1.0f / sqrtf(var + 1e-5f);
    float gg = g1[c], bb = b1[c];
    scs[c] = r * gg;
    shs[c] = bb - mu * r * gg;
  }
  __syncthreads();

  for (int t = tid; t < 8 * CH1; t += 256) {
    int rr = t / CH1, c = t % CH1;
    float v = y1[(size_t)(m0 + rr) * CH1 + c];
    yn[rr][c] = fmaxf(v * scs[c] + shs[c], 0.0f);
  }
  __syncthreads();

  const int c = tid & 127, rg = tid >> 7;   // rg in {0,1}: rows rg*4 .. rg*4+3
  float acc[4];
  #pragma unroll
  for (int r = 0; r < 4; r++) acc[r] = 0.0f;

  #pragma unroll 8
  for (int k = 0; k < CH1; k++) {
    float wv = w2T[(size_t)k * CH2 + c];
    #pragma unroll
    for (int r = 0; r < 4; r++) acc[r] += yn[rg*4 + r][k] * wv;
  }

  float s = 0.0f, ss = 0.0f;
  #pragma unroll
  for (int r = 0; r < 4; r++) {
    z[(size_t)(m0 + rg*4 + r) * CH2 + c] = acc[r];
    s += acc[r]; ss += acc[r] * acc[r];
  }
  atomicAdd(&stats2[c],       s);
  atomicAdd(&stats2[CH2 + c], ss);
}

// ---------------- Kernel D: BN2 apply + ReLU -> f32 out ----------------
__global__ void kD(const float* __restrict__ z,
                   const float* __restrict__ stats2,
                   const float* __restrict__ g2,
                   const float* __restrict__ b2,
                   float* __restrict__ out)
{
  int t = blockIdx.x * 256 + threadIdx.x;
  if (t >= M_Q * CH2) return;
  int c = t & 127;
  float s  = stats2[c], ssq = stats2[CH2 + c];
  float mu  = s  * (1.0f / M_Q);
  float var = ssq * (1.0f / M_Q) - mu * mu;
  float r   = 1.0f / sqrtf(var + 1e-5f);
  float val = fmaxf((z[t] - mu) * r * g2[c] + b2[c], 0.0f);
  out[t] = val;
}

extern "C" void kernel_launch(void* const* d_in, const int* in_sizes, int n_in,
                              void* d_out, int out_size, void* d_ws, size_t ws_size,
                              hipStream_t stream)
{
  const float* sup_xyz  = (const float*)d_in[0];
  const float* sup_feat = (const float*)d_in[1];
  const float* new_xyz  = (const float*)d_in[2];
  const float* w1       = (const float*)d_in[3];
  const float* g1       = (const float*)d_in[4];
  const float* b1       = (const float*)d_in[5];
  const float* w2       = (const float*)d_in[6];
  const float* g2       = (const float*)d_in[7];
  const float* b2       = (const float*)d_in[8];
  float* out = (float*)d_out;

  char* ws = (char*)d_ws;
  float* y1     = (float*)(ws);                       // 14,155,776 B
  float* z      = (float*)(ws + 14155776);            //  2,097,152 B (aliased by w1T early)
  float* w2T    = (float*)(ws + 16252928);            //    442,368 B
  float* stats  = (float*)(ws + 16695296);            //      7,936 B (1984 f32)
  int*   counts = (int*)  (ws + 16703232);            //        576 B
  int*   cursor = (int*)  (ws + 16703808);            //        576 B
  int*   starts = (int*)  (ws + 16704384);            //        580 B
  float* xs     = (float*)(ws + 16704964);            //     65,536 B
  float* ys     = (float*)(ws + 16770500);
  float* zs     = (float*)(ws + 16836036);
  int*   sid    = (int*)  (ws + 16901572);
  float* nnW    = (float*)(ws + 16967108);            //  1,327,104 B
  int*   nnGI   = (int*)  (ws + 18294212);            //  1,327,104 B
  float* nnLX   = (float*)(ws + 19621316);            //  3,981,312 B  (end 23,602,628)
  float* stats1 = stats;
  float* stats2 = stats + 2 * CH1;
  // w1T (141,696 B) aliases z: kA3 (last reader) runs before kC (writer of z).
  float* w1T    = z;

  // zero stats + counts + cursor in one contiguous memset
  hipMemsetAsync(stats, 0, 7936 + 576 + 576, stream);

  const int WT_TOT = CIN*CH1 + CH1*CH2;
  hipLaunchKernelGGL(kWT,     dim3((WT_TOT + 255) / 256), dim3(256), 0, stream, w1, w1T, w2, w2T);
  hipLaunchKernelGGL(kCount,  dim3((N_SUP + 255) / 256),  dim3(256), 0, stream, sup_xyz, counts);
  hipLaunchKernelGGL(kScan,   dim3(1),                    dim3(256), 0, stream, counts, starts, cursor);
  hipLaunchKernelGGL(kScatter,dim3((N_SUP + 255) / 256),  dim3(256), 0, stream, sup_xyz, cursor, xs, ys, zs, sid);
  hipLaunchKernelGGL(kA12,    dim3(M_Q),                  dim3(256), 0, stream, xs, ys, zs, sid, starts, new_xyz, nnW, nnGI, nnLX);
  hipLaunchKernelGGL(kA3,     dim3(M_Q / 8),              dim3(256), 0, stream, sup_feat, nnW, nnGI, nnLX, w1T, y1);
  hipLaunchKernelGGL(kB,      dim3(M_Q / 64),             dim3(CH1), 0, stream, y1, stats1);
  hipLaunchKernelGGL(kC,      dim3(M_Q / 8),              dim3(256), 0, stream, y1, stats1, g1, b1, w2T, z, stats2);
  hipLaunchKernelGGL(kD,      dim3((M_Q*CH2 + 255) / 256),dim3(256), 0, stream, z, stats2, g2, b2, out);
}

// Round 7
// 172.152 us; speedup vs baseline: 5.8926x; 1.0730x over previous
//
#include <hip/hip_runtime.h>
#include <hip/hip_bf16.h>

#define N_SUP 16384
#define M_Q   4096
#define TV    27
#define CIN   41
#define CH1   864
#define CH2   128
#define CAP   1024
#define NB    12          // bins per xy axis (width 50/12 = 4.17 >= 4)

// GEMM tiling for kC
#define BM 32
#define BN 128
#define BK 32
#define ASTRIDE 36        // padded LDS row stride (words) for A-tile

// grid offset value for axis-index 0/1/2 : linspace(-R+R/NV, R-R/NV, 3) = {-1.3333334, 0, +1.3333334}
__device__ __forceinline__ float gsel(int i){
  const float GOFF = (float)(-2.0 + 2.0 / 3.0);   // -1.3333334f (matches f32 linspace endpoint)
  return (i == 0) ? GOFF : ((i == 2) ? -GOFF : 0.0f);
}

// monotone bin map, identical for points and queries (monotonicity is all correctness needs)
__device__ __forceinline__ int binOf(float x){
  int b = (int)(x * (float)(NB / 50.0));
  return (b < 0) ? 0 : ((b > NB - 1) ? NB - 1 : b);
}

// branchless 3-deep insert of u64 key (keeps k0 <= k1 <= k2)
__device__ __forceinline__ void insK(unsigned long long key,
                                     unsigned long long& k0,
                                     unsigned long long& k1,
                                     unsigned long long& k2){
  bool b0 = key < k0, b1 = key < k1, b2 = key < k2;
  k2 = b1 ? k1 : (b2 ? key : k2);
  k1 = b0 ? k0 : (b1 ? key : k1);
  k0 = b0 ? key : k0;
}

// ---------------- Kernel WT: transpose w1 [864][41]->w1T [41][864] and w2 [128][864]->w2T [864][128]
__global__ void kWT(const float* __restrict__ w1, float* __restrict__ w1T,
                    const float* __restrict__ w2, float* __restrict__ w2T)
{
  int idx = blockIdx.x * 256 + threadIdx.x;
  if (idx < CIN * CH1) {
    int k = idx / CH1, t = idx % CH1;
    w1T[idx] = w1[(size_t)t * CIN + k];
  }
  int j = idx - CIN * CH1;
  if (j >= 0 && j < CH1 * CH2) {
    int k = j / CH2, c = j % CH2;
    w2T[j] = w2[(size_t)c * CH1 + k];
  }
}

// ---------------- binning: count / scan / scatter ----------------
__global__ void kCount(const float* __restrict__ sup_xyz, int* __restrict__ counts)
{
  int i = blockIdx.x * 256 + threadIdx.x;
  if (i < N_SUP) {
    float x = sup_xyz[3*i], y = sup_xyz[3*i+1];
    atomicAdd(&counts[binOf(x) * NB + binOf(y)], 1);
  }
}

__global__ void kScan(const int* __restrict__ counts, int* __restrict__ starts, int* __restrict__ cursor)
{
  __shared__ int sc[NB*NB];
  int t = threadIdx.x;
  if (t < NB*NB) sc[t] = counts[t];
  __syncthreads();
  if (t == 0) {
    int acc = 0;
    for (int b = 0; b < NB*NB; b++) { int c = sc[b]; sc[b] = acc; acc += c; }
  }
  __syncthreads();
  if (t < NB*NB) { starts[t] = sc[t]; cursor[t] = sc[t]; }
  if (t == NB*NB) starts[NB*NB] = N_SUP;
}

__global__ void kScatter(const float* __restrict__ sup_xyz, int* __restrict__ cursor,
                         float* __restrict__ xs, float* __restrict__ ys,
                         float* __restrict__ zs, int* __restrict__ sid)
{
  int i = blockIdx.x * 256 + threadIdx.x;
  if (i < N_SUP) {
    float x = sup_xyz[3*i], y = sup_xyz[3*i+1], z = sup_xyz[3*i+2];
    int b = binOf(x) * NB + binOf(y);
    int p = atomicAdd(&cursor[b], 1);
    xs[p] = x; ys[p] = y; zs[p] = z; sid[p] = i;
  }
}

// ---------------- Kernel A12: bin-pruned cube filter + per-voxel 3NN ----------------
__global__ __launch_bounds__(256) void kA12(const float* __restrict__ xs,
                                            const float* __restrict__ ys,
                                            const float* __restrict__ zs,
                                            const int*   __restrict__ sid,
                                            const int*   __restrict__ starts,
                                            const float* __restrict__ new_xyz,
                                            float* __restrict__ nnW,
                                            int*   __restrict__ nnGI,
                                            float* __restrict__ nnLX)
{
  __shared__ float4 cxyz[CAP];
  __shared__ unsigned long long sk[TV][8][3];
  __shared__ int s_cnt;

  const int m   = blockIdx.x;
  const int tid = threadIdx.x;
  if (tid == 0) s_cnt = 0;
  __syncthreads();

  const float qx = new_xyz[m*3+0];
  const float qy = new_xyz[m*3+1];
  const float qz = new_xyz[m*3+2];

  // ---- phase 1: cube filter over <=3x3 bins (z-test vacuous: |dz|<4 always) ----
  const int bx0 = binOf(qx - 4.0f), bx1 = binOf(qx + 4.0f);
  const int by0 = binOf(qy - 4.0f), by1 = binOf(qy + 4.0f);
  for (int bx = bx0; bx <= bx1; bx++) {
    const int beg = starts[bx * NB + by0];
    const int end = starts[bx * NB + by1 + 1];
    for (int i = beg + tid; i < end; i += 256) {
      float x = xs[i], y = ys[i];
      if (fabsf(__fsub_rn(x, qx)) <= 4.0f && fabsf(__fsub_rn(y, qy)) <= 4.0f) {
        int p = atomicAdd(&s_cnt, 1);
        if (p < CAP) cxyz[p] = make_float4(x, y, zs[i], __uint_as_float((unsigned)sid[i]));
      }
    }
  }
  __syncthreads();
  const int cnt = (s_cnt < CAP) ? s_cnt : CAP;

  // ---- phase 2a: strided scan, 8 threads per voxel ----
  const int v = tid >> 3, j = tid & 7;
  if (v < TV) {
    const float gx = qx + gsel(v / 9);
    const float gy = qy + gsel((v / 3) % 3);
    const float gz = qz + gsel(v % 3);
    unsigned long long k0 = ~0ull, k1 = ~0ull, k2 = ~0ull;
    for (int c = j; c < cnt; c += 8) {
      float4 f4 = cxyz[c];
      float dx = __fsub_rn(gx, f4.x);
      float dy = __fsub_rn(gy, f4.y);
      float dz = __fsub_rn(gz, f4.z);
      // forbid FMA contraction: must match numpy f32 (mul, mul, add, mul, add)
      float dd = __fadd_rn(__fadd_rn(__fmul_rn(dx,dx), __fmul_rn(dy,dy)), __fmul_rn(dz,dz));
      unsigned long long key = ((unsigned long long)__float_as_uint(dd) << 32)
                             | ((unsigned long long)__float_as_uint(f4.w) << 10)
                             | (unsigned long long)(unsigned)c;
      insK(key, k0, k1, k2);
    }
    sk[v][j][0] = k0; sk[v][j][1] = k1; sk[v][j][2] = k2;
  }
  __syncthreads();

  // ---- phase 2b: merge 8x3 keys per voxel + emit (threads 0..26) ----
  if (tid < TV) {
    const int vv = tid;
    const float gx = qx + gsel(vv / 9);
    const float gy = qy + gsel((vv / 3) % 3);
    const float gz = qz + gsel(vv % 3);
    unsigned long long k0 = ~0ull, k1 = ~0ull, k2 = ~0ull;
    #pragma unroll
    for (int jj = 0; jj < 8; jj++) {
      insK(sk[vv][jj][0], k0, k1, k2);
      insK(sk[vv][jj][1], k0, k1, k2);
      insK(sk[vv][jj][2], k0, k1, k2);
    }
    const int base = m * TV + vv;
    if (cnt > 0) {
      unsigned long long ks[3] = {k0, k1, k2};
      float d[3]; int gi[3]; int sl[3]; bool ok[3];
      #pragma unroll
      for (int r = 0; r < 3; r++) {
        unsigned db = (unsigned)(ks[r] >> 32);
        ok[r] = (db != 0xFFFFFFFFu);
        d[r]  = ok[r] ? __uint_as_float(db) : 1e10f;
        gi[r] = ok[r] ? (int)((ks[r] >> 10) & 0x3FFFull) : 0;
        sl[r] = (int)(ks[r] & 0x3FFull);
      }
      float r0 = 1.0f / (d[0] + 1e-8f);
      float r1 = 1.0f / (d[1] + 1e-8f);
      float r2 = 1.0f / (d[2] + 1e-8f);
      float den = fmaxf(r0 + r1 + r2, 1e-8f);
      nnW[base*3+0] = r0 / den; nnW[base*3+1] = r1 / den; nnW[base*3+2] = r2 / den;
      nnGI[base*3+0] = gi[0]; nnGI[base*3+1] = gi[1]; nnGI[base*3+2] = gi[2];
      #pragma unroll
      for (int r = 0; r < 3; r++) {
        if (ok[r]) {
          float4 f4 = cxyz[sl[r]];
          nnLX[base*9 + r*3 + 0] = gx - f4.x;
          nnLX[base*9 + r*3 + 1] = gy - f4.y;
          nnLX[base*9 + r*3 + 2] = gz - f4.z;
        } else {
          nnLX[base*9 + r*3 + 0] = 0.0f;
          nnLX[base*9 + r*3 + 1] = 0.0f;
          nnLX[base*9 + r*3 + 2] = 0.0f;
        }
      }
    } else {
      #pragma unroll
      for (int r = 0; r < 3; r++) {
        nnW[base*3+r] = 0.0f; nnGI[base*3+r] = 0;
        nnLX[base*9+r*3+0] = 0.0f; nnLX[base*9+r*3+1] = 0.0f; nnLX[base*9+r*3+2] = 0.0f;
      }
    }
  }
}

// ---------------- Kernel A3: interp features + grouped conv1, 8 queries per block ----------------
__global__ __launch_bounds__(256) void kA3(const float* __restrict__ sup_feat,
                                           const float* __restrict__ nnW,
                                           const int*   __restrict__ nnGI,
                                           const float* __restrict__ nnLX,
                                           const float* __restrict__ w1T,
                                           float* __restrict__ y1)
{
  __shared__ float s_feats[8][TV][CIN];   // 35,424 B
  __shared__ float s_w[8][TV][3];
  __shared__ int   s_gi[8][TV][3];

  const int m0  = blockIdx.x * 8;
  const int tid = threadIdx.x;

  for (int t = tid; t < 8*TV*3; t += 256) {
    int q = t / (TV*3), rem = t % (TV*3);
    s_w[q][rem/3][rem%3]  = nnW[m0*TV*3 + t];
    s_gi[q][rem/3][rem%3] = nnGI[m0*TV*3 + t];
  }
  for (int t = tid; t < 8*TV*9; t += 256) {
    int q = t / (TV*9), rem = t % (TV*9);
    s_feats[q][rem/9][32 + rem%9] = nnLX[m0*TV*9 + t];
  }
  __syncthreads();

  for (int t = tid; t < 8*TV*32; t += 256) {
    const int q = t / (TV*32), rem = t % (TV*32);
    const int v = rem >> 5, ch = rem & 31;
    s_feats[q][v][ch] = s_w[q][v][0] * sup_feat[s_gi[q][v][0]*32 + ch]
                      + s_w[q][v][1] * sup_feat[s_gi[q][v][1]*32 + ch]
                      + s_w[q][v][2] * sup_feat[s_gi[q][v][2]*32 + ch];
  }
  __syncthreads();

  for (int t = tid; t < CH1; t += 256) {
    const int v = t >> 5;
    float acc[8];
    #pragma unroll
    for (int q = 0; q < 8; q++) acc[q] = 0.0f;
    for (int k = 0; k < CIN; k++) {
      float w = w1T[k * CH1 + t];
      #pragma unroll
      for (int q = 0; q < 8; q++) acc[q] += s_feats[q][v][k] * w;
    }
    #pragma unroll
    for (int q = 0; q < 8; q++) y1[(size_t)(m0 + q) * CH1 + t] = acc[q];
  }
}

// ---------------- Kernel B: BN1 stats (sum, sumsq per channel over M) ----------------
__global__ void kB(const float* __restrict__ y1, float* __restrict__ stats1)
{
  const int c  = threadIdx.x;        // 864 threads
  const int m0 = blockIdx.x * 64;    // 64 blocks
  float s = 0.0f, ss = 0.0f;
  for (int r = 0; r < 64; r++) {
    float v = y1[(size_t)(m0 + r) * CH1 + c];
    s += v; ss += v * v;
  }
  atomicAdd(&stats1[c],       s);
  atomicAdd(&stats1[CH1 + c], ss);
}

// ---------------- Kernel C: BN1-fused tiled GEMM (32x128 tile, 4x4/thread) + BN2 stats ----------------
__global__ __launch_bounds__(256) void kC(const float* __restrict__ y1,
                                          const float* __restrict__ stats1,
                                          const float* __restrict__ g1,
                                          const float* __restrict__ b1,
                                          const float* __restrict__ w2T,
                                          float* __restrict__ z,
                                          float* __restrict__ stats2)
{
  __shared__ float As[BK][ASTRIDE];   //  4,608 B (padded, transposed A-tile)
  __shared__ float Bs[BK][BN];        // 16,384 B
  __shared__ float scs[CH1], shs[CH1];//  6,912 B
  __shared__ float st_s[2][BN];       //  1,024 B

  const int tid = threadIdx.x;
  const int m0  = blockIdx.x * BM;

  for (int c = tid; c < CH1; c += 256) {
    float s  = stats1[c], ssq = stats1[CH1 + c];
    float mu  = s  * (1.0f / M_Q);
    float var = ssq * (1.0f / M_Q) - mu * mu;
    float r   = 1.0f / sqrtf(var + 1e-5f);
    float gg = g1[c], bb = b1[c];
    scs[c] = r * gg;
    shs[c] = bb - mu * r * gg;
  }
  if (tid < 2*BN) st_s[tid/BN][tid%BN] = 0.0f;
  __syncthreads();

  const int tx = tid & 31;        // col group: cols tx*4..+3
  const int ty = tid >> 5;        // row group: rows ty*4..+3
  const int arow = tid >> 3;      // 0..31  (A-tile row this thread loads)
  const int acg  = (tid & 7) * 4; // 0..28  (A-tile k-offset this thread loads)

  float acc[4][4];
  #pragma unroll
  for (int i = 0; i < 4; i++)
    #pragma unroll
    for (int j = 0; j < 4; j++) acc[i][j] = 0.0f;

  for (int k0 = 0; k0 < CH1; k0 += BK) {
    // A-tile: BN1+ReLU fused, stored transposed [k][row]
    float4 a4 = *(const float4*)&y1[(size_t)(m0 + arow) * CH1 + k0 + acg];
    As[acg+0][arow] = fmaxf(a4.x * scs[k0+acg+0] + shs[k0+acg+0], 0.0f);
    As[acg+1][arow] = fmaxf(a4.y * scs[k0+acg+1] + shs[k0+acg+1], 0.0f);
    As[acg+2][arow] = fmaxf(a4.z * scs[k0+acg+2] + shs[k0+acg+2], 0.0f);
    As[acg+3][arow] = fmaxf(a4.w * scs[k0+acg+3] + shs[k0+acg+3], 0.0f);
    // B-tile: 4 float4 per thread, coalesced
    #pragma unroll
    for (int jj = 0; jj < 4; jj++) {
      int fid = tid + jj * 256;              // 0..1023
      int kk = fid >> 5, c4 = (fid & 31) * 4;
      *(float4*)&Bs[kk][c4] = *(const float4*)&w2T[(size_t)(k0 + kk) * BN + c4];
    }
    __syncthreads();

    #pragma unroll
    for (int kk = 0; kk < BK; kk++) {
      float4 av = *(const float4*)&As[kk][ty*4];
      float4 bv = *(const float4*)&Bs[kk][tx*4];
      acc[0][0] += av.x*bv.x; acc[0][1] += av.x*bv.y; acc[0][2] += av.x*bv.z; acc[0][3] += av.x*bv.w;
      acc[1][0] += av.y*bv.x; acc[1][1] += av.y*bv.y; acc[1][2] += av.y*bv.z; acc[1][3] += av.y*bv.w;
      acc[2][0] += av.z*bv.x; acc[2][1] += av.z*bv.y; acc[2][2] += av.z*bv.z; acc[2][3] += av.z*bv.w;
      acc[3][0] += av.w*bv.x; acc[3][1] += av.w*bv.y; acc[3][2] += av.w*bv.z; acc[3][3] += av.w*bv.w;
    }
    __syncthreads();
  }

  // epilogue: write z, LDS-reduce BN2 partial stats
  float s[4] = {0,0,0,0}, ss[4] = {0,0,0,0};
  #pragma unroll
  for (int i = 0; i < 4; i++) {
    float4 o = make_float4(acc[i][0], acc[i][1], acc[i][2], acc[i][3]);
    *(float4*)&z[(size_t)(m0 + ty*4 + i) * CH2 + tx*4] = o;
    #pragma unroll
    for (int j = 0; j < 4; j++) { s[j] += acc[i][j]; ss[j] += acc[i][j]*acc[i][j]; }
  }
  #pragma unroll
  for (int j = 0; j < 4; j++) {
    atomicAdd(&st_s[0][tx*4+j], s[j]);
    atomicAdd(&st_s[1][tx*4+j], ss[j]);
  }
  __syncthreads();
  if (tid < BN) {
    atomicAdd(&stats2[tid],       st_s[0][tid]);
    atomicAdd(&stats2[CH2 + tid], st_s[1][tid]);
  }
}

// ---------------- Kernel D: BN2 apply + ReLU -> f32 out ----------------
__global__ void kD(const float* __restrict__ z,
                   const float* __restrict__ stats2,
                   const float* __restrict__ g2,
                   const float* __restrict__ b2,
                   float* __restrict__ out)
{
  int t = blockIdx.x * 256 + threadIdx.x;
  if (t >= M_Q * CH2) return;
  int c = t & 127;
  float s  = stats2[c], ssq = stats2[CH2 + c];
  float mu  = s  * (1.0f / M_Q);
  float var = ssq * (1.0f / M_Q) - mu * mu;
  float r   = 1.0f / sqrtf(var + 1e-5f);
  float val = fmaxf((z[t] - mu) * r * g2[c] + b2[c], 0.0f);
  out[t] = val;
}

extern "C" void kernel_launch(void* const* d_in, const int* in_sizes, int n_in,
                              void* d_out, int out_size, void* d_ws, size_t ws_size,
                              hipStream_t stream)
{
  const float* sup_xyz  = (const float*)d_in[0];
  const float* sup_feat = (const float*)d_in[1];
  const float* new_xyz  = (const float*)d_in[2];
  const float* w1       = (const float*)d_in[3];
  const float* g1       = (const float*)d_in[4];
  const float* b1       = (const float*)d_in[5];
  const float* w2       = (const float*)d_in[6];
  const float* g2       = (const float*)d_in[7];
  const float* b2       = (const float*)d_in[8];
  float* out = (float*)d_out;

  char* ws = (char*)d_ws;
  float* y1     = (float*)(ws);                       // 14,155,776 B
  float* z      = (float*)(ws + 14155776);            //  2,097,152 B (aliased by w1T early)
  float* w2T    = (float*)(ws + 16252928);            //    442,368 B
  float* stats  = (float*)(ws + 16695296);            //      7,936 B (1984 f32)
  int*   counts = (int*)  (ws + 16703232);            //        576 B
  int*   cursor = (int*)  (ws + 16703808);            //        576 B
  int*   starts = (int*)  (ws + 16704384);            //        580 B
  float* xs     = (float*)(ws + 16704964);            //     65,536 B
  float* ys     = (float*)(ws + 16770500);
  float* zs     = (float*)(ws + 16836036);
  int*   sid    = (int*)  (ws + 16901572);
  float* nnW    = (float*)(ws + 16967108);            //  1,327,104 B
  int*   nnGI   = (int*)  (ws + 18294212);            //  1,327,104 B
  float* nnLX   = (float*)(ws + 19621316);            //  3,981,312 B  (end 23,602,628)
  float* stats1 = stats;
  float* stats2 = stats + 2 * CH1;
  // w1T (141,696 B) aliases z: kA3 (last reader) runs before kC (writer of z).
  float* w1T    = z;

  // zero stats + counts + cursor in one contiguous memset
  hipMemsetAsync(stats, 0, 7936 + 576 + 576, stream);

  const int WT_TOT = CIN*CH1 + CH1*CH2;
  hipLaunchKernelGGL(kWT,     dim3((WT_TOT + 255) / 256), dim3(256), 0, stream, w1, w1T, w2, w2T);
  hipLaunchKernelGGL(kCount,  dim3((N_SUP + 255) / 256),  dim3(256), 0, stream, sup_xyz, counts);
  hipLaunchKernelGGL(kScan,   dim3(1),                    dim3(256), 0, stream, counts, starts, cursor);
  hipLaunchKernelGGL(kScatter,dim3((N_SUP + 255) / 256),  dim3(256), 0, stream, sup_xyz, cursor, xs, ys, zs, sid);
  hipLaunchKernelGGL(kA12,    dim3(M_Q),                  dim3(256), 0, stream, xs, ys, zs, sid, starts, new_xyz, nnW, nnGI, nnLX);
  hipLaunchKernelGGL(kA3,     dim3(M_Q / 8),              dim3(256), 0, stream, sup_feat, nnW, nnGI, nnLX, w1T, y1);
  hipLaunchKernelGGL(kB,      dim3(M_Q / 64),             dim3(CH1), 0, stream, y1, stats1);
  hipLaunchKernelGGL(kC,      dim3(M_Q / BM),             dim3(256), 0, stream, y1, stats1, g1, b1, w2T, z, stats2);
  hipLaunchKernelGGL(kD,      dim3((M_Q*CH2 + 255) / 256),dim3(256), 0, stream, z, stats2, g2, b2, out);
}